// Round 5
// baseline (808.858 us; speedup 1.0000x reference)
//
#include <hip/hip_runtime.h>

#define THREADS 256
#define NPART 8
#define SC_BLOCKS 1024

static __device__ __forceinline__ int imax(int a, int b){ return a > b ? a : b; }
static __device__ __forceinline__ int imin(int a, int b){ return a < b ? a : b; }

// ---------------- CSR build ----------------

__global__ void k_zero(int* __restrict__ p, int n){
    int i = blockIdx.x * blockDim.x + threadIdx.x;
    if (i < n) p[i] = 0;
}

// 8 edges/thread, block-contiguous: independent fire-and-forget atomics
__global__ void k_hist(const int* __restrict__ es, const int* __restrict__ ed,
                       int* __restrict__ cu, int* __restrict__ cc, int E){
    const int base = blockIdx.x * (THREADS * 8) + threadIdx.x;
    if (base + 7 * THREADS < E){
        #pragma unroll
        for (int k = 0; k < 8; k++){
            int i = base + k * THREADS;
            int s = __builtin_nontemporal_load(&es[i]);
            int d = __builtin_nontemporal_load(&ed[i]);
            atomicAdd(&cu[s], 1); atomicAdd(&cc[d], 1);
        }
    } else {
        #pragma unroll
        for (int k = 0; k < 8; k++){
            int i = base + k * THREADS;
            if (i < E){ atomicAdd(&cu[es[i]], 1); atomicAdd(&cc[ed[i]], 1); }
        }
    }
}

// single-block exclusive scan; cnt_in may alias off/cur (per-index owner read-before-write)
__global__ void k_scan_small(const int* __restrict__ cnt_in, int* __restrict__ off,
                             int* __restrict__ cur, int n){
    __shared__ int ssum[THREADS];
    int t = threadIdx.x;
    int chunk = (n + THREADS - 1) / THREADS;
    int lo = t * chunk, hi = imin(lo + chunk, n);
    int s = 0;
    for (int i = lo; i < hi; i++) s += cnt_in[i];
    ssum[t] = s; __syncthreads();
    for (int d = 1; d < THREADS; d <<= 1){
        int v = (t >= d) ? ssum[t - d] : 0;
        __syncthreads();
        if (t >= d) ssum[t] += v;
        __syncthreads();
    }
    int base = t ? ssum[t - 1] : 0;
    for (int i = lo; i < hi; i++){
        int c = cnt_in[i];
        off[i] = base; cur[i] = base;
        base += c;
    }
    if (t == THREADS - 1) off[n] = base;
}

__global__ void k_scan1(const int* __restrict__ cnt, int* __restrict__ bsum, int n){
    __shared__ int red[THREADS];
    int t = threadIdx.x;
    int base = blockIdx.x * 2048;
    int s = 0;
    #pragma unroll
    for (int k = 0; k < 8; k++){ int i = base + t * 8 + k; if (i < n) s += cnt[i]; }
    red[t] = s; __syncthreads();
    for (int d = THREADS >> 1; d > 0; d >>= 1){
        if (t < d) red[t] += red[t + d];
        __syncthreads();
    }
    if (t == 0) bsum[blockIdx.x] = red[0];
}

__global__ void k_scan3(const int* __restrict__ cnt, const int* __restrict__ bsum,
                        int* __restrict__ off, int* __restrict__ cur, int n, int total){
    __shared__ int red[THREADS];
    int t = threadIdx.x;
    int base0 = blockIdx.x * 2048;
    int loc[8]; int s = 0;
    #pragma unroll
    for (int k = 0; k < 8; k++){ int i = base0 + t * 8 + k; loc[k] = (i < n) ? cnt[i] : 0; s += loc[k]; }
    red[t] = s; __syncthreads();
    for (int d = 1; d < THREADS; d <<= 1){
        int v = (t >= d) ? red[t - d] : 0;
        __syncthreads();
        if (t >= d) red[t] += v;
        __syncthreads();
    }
    int run = bsum[blockIdx.x] + (t ? red[t - 1] : 0);
    #pragma unroll
    for (int k = 0; k < 8; k++){
        int i = base0 + t * 8 + k;
        if (i < n){ off[i] = run; cur[i] = run; run += loc[k]; }
    }
    if (blockIdx.x == 0 && t == 0) off[n] = total;
}

// Persistent partitioned scatter: 1024 blocks, ALL co-resident from t=0, so the
// launch-time round-robin blockIdx%8 -> XCD binding is stable for the whole
// kernel. Partition p's 1MB CSR region is then written through exactly one
// XCD's L2: the ~16 touches/line accumulate before a single writeback.
// Edge stream is nontemporal so it doesn't evict the hot CSR lines.
__global__ __launch_bounds__(256) void k_scatter(
    const int* __restrict__ es, const int* __restrict__ ed,
    int* __restrict__ cur_c, int* __restrict__ cur_u,
    int* __restrict__ csr_c, int* __restrict__ csr_u,
    int E, float cf, float uf)
{
    const int p = blockIdx.x & (NPART - 1);
    const int slot = blockIdx.x >> 3;
    const int nslots = gridDim.x >> 3;
    const int csz = THREADS * 8;
    const int nchunks = (E + csz - 1) / csz;
    for (int ch = slot; ch < nchunks; ch += nslots){
        const int base = ch * csz + threadIdx.x;
        int s[8], d[8];
        #pragma unroll
        for (int k = 0; k < 8; k++){
            int i = base + k * THREADS;
            if (i < E){ s[k] = __builtin_nontemporal_load(&es[i]); d[k] = __builtin_nontemporal_load(&ed[i]); }
        }
        #pragma unroll
        for (int k = 0; k < 8; k++){
            int i = base + k * THREADS;
            if (i < E){
                int pd = imin((int)((float)d[k] * cf), NPART - 1);
                if (pd == p) csr_c[atomicAdd(&cur_c[d[k]], 1)] = s[k];
            }
        }
        #pragma unroll
        for (int k = 0; k < 8; k++){
            int i = base + k * THREADS;
            if (i < E){
                int ps = imin((int)((float)s[k] * uf), NPART - 1);
                if (ps == p) csr_u[atomicAdd(&cur_u[s[k]], 1)] = d[k];
            }
        }
    }
}

// ---------------- feature fusion (courses only; xu computed on the fly) ----------------

__global__ void k_xc(const float* __restrict__ cx, const float* __restrict__ cemb,
                     const int* __restrict__ cidx, const float* __restrict__ Wc,
                     const float* __restrict__ bc, float* __restrict__ xc, int NC){
    int i = blockIdx.x * blockDim.x + threadIdx.x;
    if (i >= NC * 32) return;
    int c = i >> 5, f = i & 31;
    float v;
    if (f < 16) v = cemb[cidx[c] * 16 + f];
    else { int o = f - 16; v = bc[o] + cx[c * 2 + 0] * Wc[o * 2 + 0] + cx[c * 2 + 1] * Wc[o * 2 + 1]; }
    xc[i] = v;
}

// ---------------- layer 1 course side ----------------
// linearity: mean(concat(emb, ux@Wu.T+bu)) = concat(mean emb, (mean ux)@Wu.T+bu)
// -> aggregate 21 raw dims per edge (16 embed + 5 raw ux), one matvec per course.

__global__ __launch_bounds__(256) void k_course_l1(
    const int* __restrict__ off_c, const int* __restrict__ csr_c,
    const float* __restrict__ uemb, const int* __restrict__ uidx,
    const float* __restrict__ ux, const float* __restrict__ Wu, const float* __restrict__ bu,
    const float* __restrict__ Wl, const float* __restrict__ bl, const float* __restrict__ Wr,
    const float* __restrict__ Acoef /*c2r_Wl*/, const float* __restrict__ Bcoef /*c2e_Wr*/,
    const float* __restrict__ xc,
    float* __restrict__ hc2r, float* __restrict__ hcWr, int NC)
{
    __shared__ float sWlT[1024], sWrT[1024], sAT[512], sBT[512], sWu[80], sbu[16], sbl[32];
    __shared__ float part[256];
    __shared__ float agg[32], aggx[8], hc[32];
    int t = threadIdx.x;
    for (int i = t; i < 1024; i += 256){ int o = i >> 5, k = i & 31; sWlT[k * 32 + o] = Wl[i]; sWrT[k * 32 + o] = Wr[i]; }
    for (int i = t; i < 512;  i += 256){ int j = i >> 5, o = i & 31; sAT[o * 16 + j] = Acoef[i]; sBT[o * 16 + j] = Bcoef[i]; }
    if (t < 80) sWu[t] = Wu[t];
    if (t < 16) sbu[t] = bu[t];
    if (t < 32) sbl[t] = bl[t];
    __syncthreads();
    int el = t >> 5, f = t & 31;   // 8 edge-lanes x 32 features (21 active in gather)
    for (int c = blockIdx.x; c < NC; c += gridDim.x){
        int lo = off_c[c], hi = off_c[c + 1];
        float acc = 0.f;
        if (f < 21){
            int j = lo + el;
            for (; j + 24 < hi; j += 32){             // 4 independent gather chains
                int s0 = __builtin_nontemporal_load(&csr_c[j]);
                int s1 = __builtin_nontemporal_load(&csr_c[j + 8]);
                int s2 = __builtin_nontemporal_load(&csr_c[j + 16]);
                int s3 = __builtin_nontemporal_load(&csr_c[j + 24]);
                float v0, v1, v2, v3;
                if (f < 16){
                    v0 = uemb[uidx[s0] * 16 + f]; v1 = uemb[uidx[s1] * 16 + f];
                    v2 = uemb[uidx[s2] * 16 + f]; v3 = uemb[uidx[s3] * 16 + f];
                } else {
                    v0 = ux[s0 * 5 + (f - 16)]; v1 = ux[s1 * 5 + (f - 16)];
                    v2 = ux[s2 * 5 + (f - 16)]; v3 = ux[s3 * 5 + (f - 16)];
                }
                acc += (v0 + v1) + (v2 + v3);
            }
            for (; j < hi; j += 8){
                int s0 = __builtin_nontemporal_load(&csr_c[j]);
                acc += (f < 16) ? uemb[uidx[s0] * 16 + f] : ux[s0 * 5 + (f - 16)];
            }
        }
        part[t] = acc; __syncthreads();
        float inv = 1.f / (float)imax(hi - lo, 1);
        if (el == 0 && f < 21){
            float s2 = part[f];
            #pragma unroll
            for (int k = 1; k < 8; k++) s2 += part[k * 32 + f];
            s2 *= inv;
            if (f < 16) agg[f] = s2; else aggx[f - 16] = s2;
        }
        __syncthreads();
        if (t < 16){
            float d = sbu[t];
            #pragma unroll
            for (int k = 0; k < 5; k++) d += aggx[k] * sWu[t * 5 + k];
            agg[16 + t] = d;
        }
        __syncthreads();
        if (t < 32){
            float h = sbl[t];
            for (int k = 0; k < 32; k++) h += agg[k] * sWlT[k * 32 + t] + xc[c * 32 + k] * sWrT[k * 32 + t];
            hc[t] = fmaxf(h, 0.f);
        }
        __syncthreads();
        if (t < 16){
            float a = 0.f, b = 0.f;
            for (int o = 0; o < 32; o++){ float h = hc[o]; a += h * sAT[o * 16 + t]; b += h * sBT[o * 16 + t]; }
            hc2r[c * 16 + t] = a; hcWr[c * 16 + t] = b;
        }
        __syncthreads();
    }
}

// ---------------- fused user side: one csr_u walk does L1 agg(xc) AND L2 agg(hc2r) ----------------
// outputs: hu2e = hu @ c2e_Wl.T (for course L2), ou = mean(hc2r)+c2r_bl+hu@c2r_Wr.T (final)

__global__ __launch_bounds__(256) void k_user_fused(
    const int* __restrict__ off_u, const int* __restrict__ csr_u,
    const float* __restrict__ xc, const float* __restrict__ hc2r,
    const float* __restrict__ uemb, const int* __restrict__ uidx,
    const float* __restrict__ ux, const float* __restrict__ Wu, const float* __restrict__ bu,
    const float* __restrict__ Wl, const float* __restrict__ bl, const float* __restrict__ Wr, // c1r
    const float* __restrict__ Acoef /*c2e_Wl*/, const float* __restrict__ Bcoef /*c2r_Wr*/,
    const float* __restrict__ bl2 /*c2r_bl*/,
    float* __restrict__ hu2e, float* __restrict__ ou, int NU)
{
    __shared__ float sWlT[1024], sWrT[1024], sAT[512], sBT[512], sWu[80], sbu[16], sbl[32], sbl2[16];
    __shared__ float agg[16][33], xu[16][33], hu[16][33];
    int t = threadIdx.x;
    for (int i = t; i < 1024; i += 256){ int o = i >> 5, k = i & 31; sWlT[k * 32 + o] = Wl[i]; sWrT[k * 32 + o] = Wr[i]; }
    for (int i = t; i < 512;  i += 256){ int j = i >> 5, o = i & 31; sAT[o * 16 + j] = Acoef[i]; sBT[o * 16 + j] = Bcoef[i]; }
    if (t < 80) sWu[t] = Wu[t];
    if (t < 16) sbu[t] = bu[t];
    if (t < 32) sbl[t] = bl[t];
    if (t < 16) sbl2[t] = bl2[t];
    __syncthreads();
    int ul = t >> 4, f = t & 15;   // 16 users/block, 16 lanes each
    for (int u0 = blockIdx.x * 16; u0 < NU; u0 += gridDim.x * 16){
        int u = u0 + ul;
        float b0 = 0.f, inv = 1.f;
        if (u < NU){
            int lo = off_u[u], hi = off_u[u + 1];
            float a0 = 0.f, a1 = 0.f;
            int j = lo;
            for (; j + 3 < hi; j += 4){            // 4 independent chains (12 gathers in flight)
                int d0 = csr_u[j], d1 = csr_u[j + 1], d2 = csr_u[j + 2], d3 = csr_u[j + 3];
                a0 += xc[d0 * 32 + f]      + xc[d1 * 32 + f]      + xc[d2 * 32 + f]      + xc[d3 * 32 + f];
                a1 += xc[d0 * 32 + 16 + f] + xc[d1 * 32 + 16 + f] + xc[d2 * 32 + 16 + f] + xc[d3 * 32 + 16 + f];
                b0 += hc2r[d0 * 16 + f]    + hc2r[d1 * 16 + f]    + hc2r[d2 * 16 + f]    + hc2r[d3 * 16 + f];
            }
            for (; j < hi; j++){
                int d0 = csr_u[j];
                a0 += xc[d0 * 32 + f]; a1 += xc[d0 * 32 + 16 + f]; b0 += hc2r[d0 * 16 + f];
            }
            inv = 1.f / (float)imax(hi - lo, 1);
            agg[ul][f] = a0 * inv; agg[ul][f + 16] = a1 * inv;
            xu[ul][f] = uemb[uidx[u] * 16 + f];
            float d2v = sbu[f];
            #pragma unroll
            for (int k = 0; k < 5; k++) d2v += ux[u * 5 + k] * sWu[f * 5 + k];
            xu[ul][f + 16] = d2v;
        }
        __syncthreads();
        if (u < NU){
            float h0 = sbl[f], h1 = sbl[f + 16];
            for (int k = 0; k < 32; k++){
                float ag = agg[ul][k], xv = xu[ul][k];
                h0 += ag * sWlT[k * 32 + f]      + xv * sWrT[k * 32 + f];
                h1 += ag * sWlT[k * 32 + f + 16] + xv * sWrT[k * 32 + f + 16];
            }
            hu[ul][f] = fmaxf(h0, 0.f); hu[ul][f + 16] = fmaxf(h1, 0.f);
        }
        __syncthreads();
        if (u < NU){
            float a = 0.f, b = 0.f;
            for (int o = 0; o < 32; o++){ float h = hu[ul][o]; a += h * sAT[o * 16 + f]; b += h * sBT[o * 16 + f]; }
            hu2e[u * 16 + f] = a;
            ou[u * 16 + f] = b0 * inv + sbl2[f] + b;
        }
        __syncthreads();
    }
}

// ---------------- layer 2 course side ----------------

__global__ __launch_bounds__(256) void k_course_l2(
    const int* __restrict__ off_c, const int* __restrict__ csr_c,
    const float* __restrict__ hu2e, const float* __restrict__ bl2,
    const float* __restrict__ hcWr, float* __restrict__ oc, int NC)
{
    __shared__ float part[256];
    int t = threadIdx.x; int el = t >> 4, f = t & 15;  // 16 edge-lanes x 16 features
    for (int c = blockIdx.x; c < NC; c += gridDim.x){
        int lo = off_c[c], hi = off_c[c + 1];
        float acc = 0.f;
        int j = lo + el;
        for (; j + 48 < hi; j += 64){              // 4 independent gather chains
            int s0 = __builtin_nontemporal_load(&csr_c[j]);
            int s1 = __builtin_nontemporal_load(&csr_c[j + 16]);
            int s2 = __builtin_nontemporal_load(&csr_c[j + 32]);
            int s3 = __builtin_nontemporal_load(&csr_c[j + 48]);
            acc += hu2e[s0 * 16 + f] + hu2e[s1 * 16 + f]
                 + hu2e[s2 * 16 + f] + hu2e[s3 * 16 + f];
        }
        for (; j < hi; j += 16){
            int s0 = __builtin_nontemporal_load(&csr_c[j]);
            acc += hu2e[s0 * 16 + f];
        }
        part[t] = acc; __syncthreads();
        if (el == 0){
            float s = part[f];
            #pragma unroll
            for (int k = 1; k < 16; k++) s += part[k * 16 + f];
            oc[c * 16 + f] = s / (float)imax(hi - lo, 1) + bl2[f] + hcWr[c * 16 + f];
        }
        __syncthreads();
    }
}

// ---------------- decode: dot(ou[ls], oc[ld]) ----------------

__global__ void k_decode(const int* __restrict__ ls, const int* __restrict__ ld,
                         const float* __restrict__ ou, const float* __restrict__ oc,
                         float* __restrict__ out, int L){
    int gt = blockIdx.x * blockDim.x + threadIdx.x;
    int l = gt >> 2, q = gt & 3;
    if (l >= L) return;
    int a = ls[l], b = ld[l];
    float4 va = ((const float4*)(ou + (size_t)a * 16))[q];
    float4 vb = ((const float4*)(oc + (size_t)b * 16))[q];
    float s = va.x * vb.x + va.y * vb.y + va.z * vb.z + va.w * vb.w;
    s += __shfl_xor(s, 1);
    s += __shfl_xor(s, 2);
    if (q == 0) out[l] = s;
}

// ---------------- launcher ----------------

extern "C" void kernel_launch(void* const* d_in, const int* in_sizes, int n_in,
                              void* d_out, int out_size, void* d_ws, size_t ws_size,
                              hipStream_t stream)
{
    const float* user_x       = (const float*)d_in[0];
    const float* course_x     = (const float*)d_in[1];
    const float* user_embed   = (const float*)d_in[2];
    const float* course_embed = (const float*)d_in[3];
    const float* Wu = (const float*)d_in[4];
    const float* bu = (const float*)d_in[5];
    const float* Wc = (const float*)d_in[6];
    const float* bc = (const float*)d_in[7];
    const float* c1e_Wl = (const float*)d_in[8];
    const float* c1e_bl = (const float*)d_in[9];
    const float* c1e_Wr = (const float*)d_in[10];
    const float* c1r_Wl = (const float*)d_in[11];
    const float* c1r_bl = (const float*)d_in[12];
    const float* c1r_Wr = (const float*)d_in[13];
    const float* c2e_Wl = (const float*)d_in[14];
    const float* c2e_bl = (const float*)d_in[15];
    const float* c2e_Wr = (const float*)d_in[16];
    const float* c2r_Wl = (const float*)d_in[17];
    const float* c2r_bl = (const float*)d_in[18];
    const float* c2r_Wr = (const float*)d_in[19];
    const int* uidx      = (const int*)d_in[20];
    const int* cidx      = (const int*)d_in[21];
    const int* edge_src  = (const int*)d_in[22];
    const int* edge_dst  = (const int*)d_in[23];
    const int* label_src = (const int*)d_in[24];
    const int* label_dst = (const int*)d_in[25];
    const int NU = in_sizes[20], NC = in_sizes[21], E = in_sizes[22], L = in_sizes[24];

    char* ws = (char*)d_ws;
    size_t woff = 0;
    auto alloc = [&](size_t bytes) -> char* {
        char* p = ws + woff;
        woff = (woff + bytes + 255) & ~(size_t)255;
        return p;
    };
    int*   off_u = (int*)  alloc((size_t)(NU + 1) * 4);
    int*   cur_u = (int*)  alloc((size_t)NU * 4);
    int*   off_c = (int*)  alloc((size_t)(NC + 1) * 4);
    int*   cur_c = (int*)  alloc((size_t)NC * 4);
    int*   csr_c = (int*)  alloc((size_t)E * 4);
    int*   csr_u = (int*)  alloc((size_t)E * 4);
    float* xc    = (float*)alloc((size_t)NC * 32 * 4);
    float* hc2r  = (float*)alloc((size_t)NC * 16 * 4);
    float* hcWr  = (float*)alloc((size_t)NC * 16 * 4);
    float* hu2e  = (float*)alloc((size_t)NU * 16 * 4);
    float* ou    = (float*)alloc((size_t)NU * 16 * 4);
    float* occ   = (float*)alloc((size_t)NC * 16 * 4);
    int*   bsum  = (int*)  alloc(4097 * 4);
    (void)ws_size; (void)n_in; (void)out_size;

    int chunks = (E + 2047) / 2048;  // 8 edges/thread blocks

    k_zero<<<(NU + 255) / 256, 256, 0, stream>>>(cur_u, NU);
    k_zero<<<(NC + 255) / 256, 256, 0, stream>>>(cur_c, NC);
    k_hist<<<chunks, 256, 0, stream>>>(edge_src, edge_dst, cur_u, cur_c, E);
    k_scan_small<<<1, 256, 0, stream>>>(cur_c, off_c, cur_c, NC);
    int nb = (NU + 2047) / 2048;
    k_scan1<<<nb, 256, 0, stream>>>(cur_u, bsum, NU);
    k_scan_small<<<1, 256, 0, stream>>>(bsum, bsum, bsum, nb);
    k_scan3<<<nb, 256, 0, stream>>>(cur_u, bsum, off_u, cur_u, NU, E);
    k_xc<<<(NC * 32 + 255) / 256, 256, 0, stream>>>(course_x, course_embed, cidx, Wc, bc, xc, NC);
    k_scatter<<<SC_BLOCKS, 256, 0, stream>>>(edge_src, edge_dst, cur_c, cur_u, csr_c, csr_u,
                                             E, (float)NPART / (float)NC, (float)NPART / (float)NU);
    k_course_l1<<<2048, 256, 0, stream>>>(off_c, csr_c, user_embed, uidx, user_x, Wu, bu,
                                          c1e_Wl, c1e_bl, c1e_Wr, c2r_Wl, c2e_Wr, xc, hc2r, hcWr, NC);
    k_user_fused<<<2048, 256, 0, stream>>>(off_u, csr_u, xc, hc2r, user_embed, uidx, user_x, Wu, bu,
                                           c1r_Wl, c1r_bl, c1r_Wr, c2e_Wl, c2r_Wr, c2r_bl, hu2e, ou, NU);
    k_course_l2<<<1024, 256, 0, stream>>>(off_c, csr_c, hu2e, c2e_bl, hcWr, occ, NC);
    k_decode<<<(unsigned)(((size_t)L * 4 + 255) / 256), 256, 0, stream>>>(label_src, label_dst, ou, occ, (float*)d_out, L);
}

// Round 6
// 529.080 us; speedup vs baseline: 1.5288x; 1.5288x over previous
//
#include <hip/hip_runtime.h>

#define THREADS 256
#define CSH 8          // course bin shift: 256 courses/bin
#define USH 13         // user bin shift: 8192 users/bin
#define MAXBIN 64

static __device__ __forceinline__ int imax(int a, int b){ return a > b ? a : b; }
static __device__ __forceinline__ int imin(int a, int b){ return a < b ? a : b; }

// ---------------- CSR build: 2-pass LDS radix ----------------

// Phase 0: coarse bin histograms (LDS-aggregated, ~100 global atomics/block)
__global__ __launch_bounds__(256) void k_phase0(const int* __restrict__ es, const int* __restrict__ ed,
                                                int* __restrict__ cnt_c, int* __restrict__ cnt_u,
                                                int E, int NBC, int NBU){
    __shared__ int hc[MAXBIN], hu[MAXBIN];
    int t = threadIdx.x;
    int base = blockIdx.x * 2048 + t;
    if (t < MAXBIN){ hc[t] = 0; hu[t] = 0; }
    __syncthreads();
    #pragma unroll
    for (int k = 0; k < 8; k++){
        int i = base + k * 256;
        if (i < E){
            int s = __builtin_nontemporal_load(&es[i]);
            int d = __builtin_nontemporal_load(&ed[i]);
            atomicAdd(&hc[d >> CSH], 1); atomicAdd(&hu[s >> USH], 1);
        }
    }
    __syncthreads();
    if (t < NBC && hc[t]) atomicAdd(&cnt_c[t], hc[t]);
    if (t < NBU && hu[t]) atomicAdd(&cnt_u[t], hu[t]);
}

// tiny scan: bin bases + cur init + off sentinels
__global__ void k_sbase(const int* __restrict__ cnt_c, const int* __restrict__ cnt_u,
                        int* __restrict__ base_c, int* __restrict__ cur_c,
                        int* __restrict__ base_u, int* __restrict__ cur_u,
                        int* __restrict__ off_c, int* __restrict__ off_u,
                        int NC, int NU, int NBC, int NBU, int E){
    if (threadIdx.x == 0){
        int a = 0;
        for (int b = 0; b < NBC; b++){ base_c[b] = a; cur_c[b] = a; a += cnt_c[b]; }
        a = 0;
        for (int b = 0; b < NBU; b++){ base_u[b] = a; cur_u[b] = a; a += cnt_u[b]; }
        off_c[NC] = E; off_u[NU] = E;
    }
}

// Phase 1: LDS radix pass. Block sorts its 2048 edges by coarse bin, reserves a
// contiguous run per bin (1 atomic/bin), writes bin-grouped packed (src,dst)
// records: consecutive LDS slots -> consecutive global addresses (dense).
__global__ __launch_bounds__(256) void k_phase1(const int* __restrict__ es, const int* __restrict__ ed,
                                                int* __restrict__ cur_c, int* __restrict__ cur_u,
                                                uint2* __restrict__ binned_c, uint2* __restrict__ binned_u,
                                                int E, int NBC, int NBU){
    __shared__ uint2 stc[2048], stu[2048];
    __shared__ int hc[MAXBIN], scc[MAXBIN], lcc[MAXBIN], gbc[MAXBIN];
    __shared__ int hu[MAXBIN], scu[MAXBIN], lcu[MAXBIN], gbu[MAXBIN];
    int t = threadIdx.x;
    int base = blockIdx.x * 2048 + t;
    int s[8], d[8];
    #pragma unroll
    for (int k = 0; k < 8; k++){
        int i = base + k * 256;
        if (i < E){ s[k] = __builtin_nontemporal_load(&es[i]); d[k] = __builtin_nontemporal_load(&ed[i]); }
    }
    if (t < MAXBIN){ hc[t] = 0; hu[t] = 0; }
    __syncthreads();
    #pragma unroll
    for (int k = 0; k < 8; k++){
        int i = base + k * 256;
        if (i < E){ atomicAdd(&hc[d[k] >> CSH], 1); atomicAdd(&hu[s[k] >> USH], 1); }
    }
    __syncthreads();
    if (t == 0){ int a = 0; for (int b = 0; b < NBC; b++){ scc[b] = a; a += hc[b]; } }
    if (t == 1){ int a = 0; for (int b = 0; b < NBU; b++){ scu[b] = a; a += hu[b]; } }
    __syncthreads();
    if (t < NBC){ lcc[t] = scc[t]; gbc[t] = atomicAdd(&cur_c[t], hc[t]); }
    if (t < NBU){ lcu[t] = scu[t]; gbu[t] = atomicAdd(&cur_u[t], hu[t]); }
    __syncthreads();
    #pragma unroll
    for (int k = 0; k < 8; k++){
        int i = base + k * 256;
        if (i < E){
            int p = atomicAdd(&lcc[d[k] >> CSH], 1); stc[p] = make_uint2((unsigned)s[k], (unsigned)d[k]);
            int q = atomicAdd(&lcu[s[k] >> USH], 1); stu[q] = make_uint2((unsigned)s[k], (unsigned)d[k]);
        }
    }
    __syncthreads();
    int nv = imin(2048, E - blockIdx.x * 2048);
    for (int i = t; i < nv; i += 256){
        uint2 e = stc[i]; int b  = (int)(e.y >> CSH); binned_c[gbc[b]  + (i - scc[b])]  = e;
        uint2 f = stu[i]; int b2 = (int)(f.x >> USH); binned_u[gbu[b2] + (i - scu[b2])] = f;
    }
}

// Phase 2: one block per bin. Exact per-node CSR inside an L2-resident window.
// Local LDS histogram + scan directly yields off_c/off_u (no global scan kernels).
__global__ __launch_bounds__(256) void k_p2(const uint2* __restrict__ binned_c, const uint2* __restrict__ binned_u,
                                            const int* __restrict__ cnt_c, const int* __restrict__ base_c,
                                            const int* __restrict__ cnt_u, const int* __restrict__ base_u,
                                            int* __restrict__ off_c, int* __restrict__ csr_c,
                                            int* __restrict__ off_u, int* __restrict__ csr_u,
                                            int NC, int NU, int NBC){
    __shared__ int lsh[8448];
    int t = threadIdx.x;
    if ((int)blockIdx.x < NBC){
        int b = blockIdx.x;
        int* lh  = lsh;        // [256]
        int* lof = lsh + 256;  // [256]
        lh[t] = 0;
        __syncthreads();
        int n = cnt_c[b], gb = base_c[b];
        const uint2* src = binned_c + gb;
        for (int i = t; i < n; i += 256) atomicAdd(&lh[src[i].y & 255], 1);
        __syncthreads();
        if (t == 0){ int a = gb; for (int c = 0; c < 256; c++){ lof[c] = a; a += lh[c]; } }
        __syncthreads();
        int gc = (b << CSH) + t;
        if (gc < NC) off_c[gc] = lof[t];
        __syncthreads();
        for (int i = t; i < n; i += 256){
            uint2 e = src[i];
            int p = atomicAdd(&lof[e.y & 255], 1);
            csr_c[p] = (int)e.x;
        }
    } else {
        int b = blockIdx.x - NBC;
        int* lh   = lsh;         // [8192]
        int* part = lsh + 8192;  // [256]
        for (int i = t; i < 8192; i += 256) lh[i] = 0;
        __syncthreads();
        int n = cnt_u[b], gb = base_u[b];
        const uint2* src = binned_u + gb;
        for (int i = t; i < n; i += 256) atomicAdd(&lh[src[i].x & 8191], 1);
        __syncthreads();
        int ps = 0;
        #pragma unroll
        for (int j = 0; j < 32; j++) ps += lh[t * 32 + j];
        part[t] = ps;
        __syncthreads();
        if (t == 0){ int a = 0; for (int k = 0; k < 256; k++){ int tmp = part[k]; part[k] = a; a += tmp; } }
        __syncthreads();
        int a2 = gb + part[t];
        #pragma unroll
        for (int j = 0; j < 32; j++){ int idx = t * 32 + j; int tmp = lh[idx]; lh[idx] = a2; a2 += tmp; }
        __syncthreads();
        int ub = b << USH;
        for (int i = t; i < 8192; i += 256){ int gu = ub + i; if (gu < NU) off_u[gu] = lh[i]; }
        __syncthreads();
        for (int i = t; i < n; i += 256){
            uint2 e = src[i];
            int p = atomicAdd(&lh[e.x & 8191], 1);
            csr_u[p] = (int)e.y;
        }
    }
}

// ---------------- feature fusion (courses only; xu computed on the fly) ----------------

__global__ void k_xc(const float* __restrict__ cx, const float* __restrict__ cemb,
                     const int* __restrict__ cidx, const float* __restrict__ Wc,
                     const float* __restrict__ bc, float* __restrict__ xc, int NC){
    int i = blockIdx.x * blockDim.x + threadIdx.x;
    if (i >= NC * 32) return;
    int c = i >> 5, f = i & 31;
    float v;
    if (f < 16) v = cemb[cidx[c] * 16 + f];
    else { int o = f - 16; v = bc[o] + cx[c * 2 + 0] * Wc[o * 2 + 0] + cx[c * 2 + 1] * Wc[o * 2 + 1]; }
    xc[i] = v;
}

// ---------------- layer 1 course side ----------------
// linearity: mean(concat(emb, ux@Wu.T+bu)) = concat(mean emb, (mean ux)@Wu.T+bu)

__global__ __launch_bounds__(256) void k_course_l1(
    const int* __restrict__ off_c, const int* __restrict__ csr_c,
    const float* __restrict__ uemb, const int* __restrict__ uidx,
    const float* __restrict__ ux, const float* __restrict__ Wu, const float* __restrict__ bu,
    const float* __restrict__ Wl, const float* __restrict__ bl, const float* __restrict__ Wr,
    const float* __restrict__ Acoef /*c2r_Wl*/, const float* __restrict__ Bcoef /*c2e_Wr*/,
    const float* __restrict__ xc,
    float* __restrict__ hc2r, float* __restrict__ hcWr, int NC)
{
    __shared__ float sWlT[1024], sWrT[1024], sAT[512], sBT[512], sWu[80], sbu[16], sbl[32];
    __shared__ float part[256];
    __shared__ float agg[32], aggx[8], hc[32];
    int t = threadIdx.x;
    for (int i = t; i < 1024; i += 256){ int o = i >> 5, k = i & 31; sWlT[k * 32 + o] = Wl[i]; sWrT[k * 32 + o] = Wr[i]; }
    for (int i = t; i < 512;  i += 256){ int j = i >> 5, o = i & 31; sAT[o * 16 + j] = Acoef[i]; sBT[o * 16 + j] = Bcoef[i]; }
    if (t < 80) sWu[t] = Wu[t];
    if (t < 16) sbu[t] = bu[t];
    if (t < 32) sbl[t] = bl[t];
    __syncthreads();
    int el = t >> 5, f = t & 31;   // 8 edge-lanes x 32 features (21 active in gather)
    for (int c = blockIdx.x; c < NC; c += gridDim.x){
        int lo = off_c[c], hi = off_c[c + 1];
        float acc = 0.f;
        if (f < 21){
            int j = lo + el;
            for (; j + 24 < hi; j += 32){             // 4 independent gather chains
                int s0 = csr_c[j], s1 = csr_c[j + 8], s2 = csr_c[j + 16], s3 = csr_c[j + 24];
                float v0, v1, v2, v3;
                if (f < 16){
                    v0 = uemb[uidx[s0] * 16 + f]; v1 = uemb[uidx[s1] * 16 + f];
                    v2 = uemb[uidx[s2] * 16 + f]; v3 = uemb[uidx[s3] * 16 + f];
                } else {
                    v0 = ux[s0 * 5 + (f - 16)]; v1 = ux[s1 * 5 + (f - 16)];
                    v2 = ux[s2 * 5 + (f - 16)]; v3 = ux[s3 * 5 + (f - 16)];
                }
                acc += (v0 + v1) + (v2 + v3);
            }
            for (; j < hi; j += 8){
                int s0 = csr_c[j];
                acc += (f < 16) ? uemb[uidx[s0] * 16 + f] : ux[s0 * 5 + (f - 16)];
            }
        }
        part[t] = acc; __syncthreads();
        float inv = 1.f / (float)imax(hi - lo, 1);
        if (el == 0 && f < 21){
            float s2 = part[f];
            #pragma unroll
            for (int k = 1; k < 8; k++) s2 += part[k * 32 + f];
            s2 *= inv;
            if (f < 16) agg[f] = s2; else aggx[f - 16] = s2;
        }
        __syncthreads();
        if (t < 16){
            float d = sbu[t];
            #pragma unroll
            for (int k = 0; k < 5; k++) d += aggx[k] * sWu[t * 5 + k];
            agg[16 + t] = d;
        }
        __syncthreads();
        if (t < 32){
            float h = sbl[t];
            for (int k = 0; k < 32; k++) h += agg[k] * sWlT[k * 32 + t] + xc[c * 32 + k] * sWrT[k * 32 + t];
            hc[t] = fmaxf(h, 0.f);
        }
        __syncthreads();
        if (t < 16){
            float a = 0.f, b = 0.f;
            for (int o = 0; o < 32; o++){ float h = hc[o]; a += h * sAT[o * 16 + t]; b += h * sBT[o * 16 + t]; }
            hc2r[c * 16 + t] = a; hcWr[c * 16 + t] = b;
        }
        __syncthreads();
    }
}

// ---------------- fused user side ----------------

__global__ __launch_bounds__(256) void k_user_fused(
    const int* __restrict__ off_u, const int* __restrict__ csr_u,
    const float* __restrict__ xc, const float* __restrict__ hc2r,
    const float* __restrict__ uemb, const int* __restrict__ uidx,
    const float* __restrict__ ux, const float* __restrict__ Wu, const float* __restrict__ bu,
    const float* __restrict__ Wl, const float* __restrict__ bl, const float* __restrict__ Wr, // c1r
    const float* __restrict__ Acoef /*c2e_Wl*/, const float* __restrict__ Bcoef /*c2r_Wr*/,
    const float* __restrict__ bl2 /*c2r_bl*/,
    float* __restrict__ hu2e, float* __restrict__ ou, int NU)
{
    __shared__ float sWlT[1024], sWrT[1024], sAT[512], sBT[512], sWu[80], sbu[16], sbl[32], sbl2[16];
    __shared__ float agg[16][33], xu[16][33], hu[16][33];
    int t = threadIdx.x;
    for (int i = t; i < 1024; i += 256){ int o = i >> 5, k = i & 31; sWlT[k * 32 + o] = Wl[i]; sWrT[k * 32 + o] = Wr[i]; }
    for (int i = t; i < 512;  i += 256){ int j = i >> 5, o = i & 31; sAT[o * 16 + j] = Acoef[i]; sBT[o * 16 + j] = Bcoef[i]; }
    if (t < 80) sWu[t] = Wu[t];
    if (t < 16) sbu[t] = bu[t];
    if (t < 32) sbl[t] = bl[t];
    if (t < 16) sbl2[t] = bl2[t];
    __syncthreads();
    int ul = t >> 4, f = t & 15;   // 16 users/block, 16 lanes each
    for (int u0 = blockIdx.x * 16; u0 < NU; u0 += gridDim.x * 16){
        int u = u0 + ul;
        float b0 = 0.f, inv = 1.f;
        if (u < NU){
            int lo = off_u[u], hi = off_u[u + 1];
            float a0 = 0.f, a1 = 0.f;
            int j = lo;
            for (; j + 3 < hi; j += 4){            // 4 independent chains
                int d0 = csr_u[j], d1 = csr_u[j + 1], d2 = csr_u[j + 2], d3 = csr_u[j + 3];
                a0 += xc[d0 * 32 + f]      + xc[d1 * 32 + f]      + xc[d2 * 32 + f]      + xc[d3 * 32 + f];
                a1 += xc[d0 * 32 + 16 + f] + xc[d1 * 32 + 16 + f] + xc[d2 * 32 + 16 + f] + xc[d3 * 32 + 16 + f];
                b0 += hc2r[d0 * 16 + f]    + hc2r[d1 * 16 + f]    + hc2r[d2 * 16 + f]    + hc2r[d3 * 16 + f];
            }
            for (; j < hi; j++){
                int d0 = csr_u[j];
                a0 += xc[d0 * 32 + f]; a1 += xc[d0 * 32 + 16 + f]; b0 += hc2r[d0 * 16 + f];
            }
            inv = 1.f / (float)imax(hi - lo, 1);
            agg[ul][f] = a0 * inv; agg[ul][f + 16] = a1 * inv;
            xu[ul][f] = uemb[uidx[u] * 16 + f];
            float d2v = sbu[f];
            #pragma unroll
            for (int k = 0; k < 5; k++) d2v += ux[u * 5 + k] * sWu[f * 5 + k];
            xu[ul][f + 16] = d2v;
        }
        __syncthreads();
        if (u < NU){
            float h0 = sbl[f], h1 = sbl[f + 16];
            for (int k = 0; k < 32; k++){
                float ag = agg[ul][k], xv = xu[ul][k];
                h0 += ag * sWlT[k * 32 + f]      + xv * sWrT[k * 32 + f];
                h1 += ag * sWlT[k * 32 + f + 16] + xv * sWrT[k * 32 + f + 16];
            }
            hu[ul][f] = fmaxf(h0, 0.f); hu[ul][f + 16] = fmaxf(h1, 0.f);
        }
        __syncthreads();
        if (u < NU){
            float a = 0.f, b = 0.f;
            for (int o = 0; o < 32; o++){ float h = hu[ul][o]; a += h * sAT[o * 16 + f]; b += h * sBT[o * 16 + f]; }
            hu2e[u * 16 + f] = a;
            ou[u * 16 + f] = b0 * inv + sbl2[f] + b;
        }
        __syncthreads();
    }
}

// ---------------- layer 2 course side ----------------

__global__ __launch_bounds__(256) void k_course_l2(
    const int* __restrict__ off_c, const int* __restrict__ csr_c,
    const float* __restrict__ hu2e, const float* __restrict__ bl2,
    const float* __restrict__ hcWr, float* __restrict__ oc, int NC)
{
    __shared__ float part[256];
    int t = threadIdx.x; int el = t >> 4, f = t & 15;  // 16 edge-lanes x 16 features
    for (int c = blockIdx.x; c < NC; c += gridDim.x){
        int lo = off_c[c], hi = off_c[c + 1];
        float acc = 0.f;
        int j = lo + el;
        for (; j + 48 < hi; j += 64){              // 4 independent gather chains
            acc += hu2e[csr_c[j] * 16 + f] + hu2e[csr_c[j + 16] * 16 + f]
                 + hu2e[csr_c[j + 32] * 16 + f] + hu2e[csr_c[j + 48] * 16 + f];
        }
        for (; j < hi; j += 16) acc += hu2e[csr_c[j] * 16 + f];
        part[t] = acc; __syncthreads();
        if (el == 0){
            float s = part[f];
            #pragma unroll
            for (int k = 1; k < 16; k++) s += part[k * 16 + f];
            oc[c * 16 + f] = s / (float)imax(hi - lo, 1) + bl2[f] + hcWr[c * 16 + f];
        }
        __syncthreads();
    }
}

// ---------------- decode: dot(ou[ls], oc[ld]) ----------------

__global__ void k_decode(const int* __restrict__ ls, const int* __restrict__ ld,
                         const float* __restrict__ ou, const float* __restrict__ oc,
                         float* __restrict__ out, int L){
    int gt = blockIdx.x * blockDim.x + threadIdx.x;
    int l = gt >> 2, q = gt & 3;
    if (l >= L) return;
    int a = ls[l], b = ld[l];
    float4 va = ((const float4*)(ou + (size_t)a * 16))[q];
    float4 vb = ((const float4*)(oc + (size_t)b * 16))[q];
    float s = va.x * vb.x + va.y * vb.y + va.z * vb.z + va.w * vb.w;
    s += __shfl_xor(s, 1);
    s += __shfl_xor(s, 2);
    if (q == 0) out[l] = s;
}

// ---------------- launcher ----------------

extern "C" void kernel_launch(void* const* d_in, const int* in_sizes, int n_in,
                              void* d_out, int out_size, void* d_ws, size_t ws_size,
                              hipStream_t stream)
{
    const float* user_x       = (const float*)d_in[0];
    const float* course_x     = (const float*)d_in[1];
    const float* user_embed   = (const float*)d_in[2];
    const float* course_embed = (const float*)d_in[3];
    const float* Wu = (const float*)d_in[4];
    const float* bu = (const float*)d_in[5];
    const float* Wc = (const float*)d_in[6];
    const float* bc = (const float*)d_in[7];
    const float* c1e_Wl = (const float*)d_in[8];
    const float* c1e_bl = (const float*)d_in[9];
    const float* c1e_Wr = (const float*)d_in[10];
    const float* c1r_Wl = (const float*)d_in[11];
    const float* c1r_bl = (const float*)d_in[12];
    const float* c1r_Wr = (const float*)d_in[13];
    const float* c2e_Wl = (const float*)d_in[14];
    const float* c2e_bl = (const float*)d_in[15];
    const float* c2e_Wr = (const float*)d_in[16];
    const float* c2r_Wl = (const float*)d_in[17];
    const float* c2r_bl = (const float*)d_in[18];
    const float* c2r_Wr = (const float*)d_in[19];
    const int* uidx      = (const int*)d_in[20];
    const int* cidx      = (const int*)d_in[21];
    const int* edge_src  = (const int*)d_in[22];
    const int* edge_dst  = (const int*)d_in[23];
    const int* label_src = (const int*)d_in[24];
    const int* label_dst = (const int*)d_in[25];
    const int NU = in_sizes[20], NC = in_sizes[21], E = in_sizes[22], L = in_sizes[24];
    const int NBC = (NC + 255) >> CSH;      // 40
    const int NBU = (NU + 8191) >> USH;     // 62

    char* ws = (char*)d_ws;
    size_t woff = 0;
    auto alloc = [&](size_t bytes) -> char* {
        char* p = ws + woff;
        woff = (woff + bytes + 255) & ~(size_t)255;
        return p;
    };
    int*   off_u = (int*)  alloc((size_t)(NU + 1) * 4);
    int*   off_c = (int*)  alloc((size_t)(NC + 1) * 4);
    int*   csr_c = (int*)  alloc((size_t)E * 4);
    int*   csr_u = (int*)  alloc((size_t)E * 4);
    float* xc    = (float*)alloc((size_t)NC * 32 * 4);
    float* hc2r  = (float*)alloc((size_t)NC * 16 * 4);
    float* hcWr  = (float*)alloc((size_t)NC * 16 * 4);
    float* hu2e  = (float*)alloc((size_t)NU * 16 * 4);   // binned_c aliases (16MB <= 32MB)
    float* ou    = (float*)alloc((size_t)NU * 16 * 4);   // binned_u aliases
    float* occ   = (float*)alloc((size_t)NC * 16 * 4);
    int*   cnt_c  = (int*) alloc(MAXBIN * 4);
    int*   cnt_u  = (int*) alloc(MAXBIN * 4);
    int*   base_c = (int*) alloc(MAXBIN * 4);
    int*   base_u = (int*) alloc(MAXBIN * 4);
    int*   cur_c  = (int*) alloc(MAXBIN * 4);
    int*   cur_u  = (int*) alloc(MAXBIN * 4);
    uint2* binned_c = (uint2*)hu2e;  // consumed by k_p2 before k_user_fused writes hu2e
    uint2* binned_u = (uint2*)ou;    // consumed by k_p2 before k_user_fused writes ou
    (void)ws_size; (void)n_in; (void)out_size;

    int chunks = (E + 2047) / 2048;

    hipMemsetAsync(cnt_c, 0, MAXBIN * 4, stream);
    hipMemsetAsync(cnt_u, 0, MAXBIN * 4, stream);
    k_phase0<<<chunks, 256, 0, stream>>>(edge_src, edge_dst, cnt_c, cnt_u, E, NBC, NBU);
    k_sbase<<<1, 64, 0, stream>>>(cnt_c, cnt_u, base_c, cur_c, base_u, cur_u, off_c, off_u, NC, NU, NBC, NBU, E);
    k_phase1<<<chunks, 256, 0, stream>>>(edge_src, edge_dst, cur_c, cur_u, binned_c, binned_u, E, NBC, NBU);
    k_xc<<<(NC * 32 + 255) / 256, 256, 0, stream>>>(course_x, course_embed, cidx, Wc, bc, xc, NC);
    k_p2<<<NBC + NBU, 256, 0, stream>>>(binned_c, binned_u, cnt_c, base_c, cnt_u, base_u,
                                        off_c, csr_c, off_u, csr_u, NC, NU, NBC);
    k_course_l1<<<2048, 256, 0, stream>>>(off_c, csr_c, user_embed, uidx, user_x, Wu, bu,
                                          c1e_Wl, c1e_bl, c1e_Wr, c2r_Wl, c2e_Wr, xc, hc2r, hcWr, NC);
    k_user_fused<<<2048, 256, 0, stream>>>(off_u, csr_u, xc, hc2r, user_embed, uidx, user_x, Wu, bu,
                                           c1r_Wl, c1r_bl, c1r_Wr, c2e_Wl, c2r_Wr, c2r_bl, hu2e, ou, NU);
    k_course_l2<<<1024, 256, 0, stream>>>(off_c, csr_c, hu2e, c2e_bl, hcWr, occ, NC);
    k_decode<<<(unsigned)(((size_t)L * 4 + 255) / 256), 256, 0, stream>>>(label_src, label_dst, ou, occ, (float*)d_out, L);
}

// Round 7
// 444.637 us; speedup vs baseline: 1.8191x; 1.1899x over previous
//
#include <hip/hip_runtime.h>

#define THREADS 256
#define CSH 8          // course bin shift: 256 courses/bin
#define USH 13         // user bin shift: 8192 users/bin
#define MAXBIN 64

typedef _Float16 half8 __attribute__((ext_vector_type(8)));
typedef float floatx4 __attribute__((ext_vector_type(4)));

static __device__ __forceinline__ int imax(int a, int b){ return a > b ? a : b; }
static __device__ __forceinline__ int imin(int a, int b){ return a < b ? a : b; }

// ---------------- CSR build: 2-pass LDS radix ----------------

__global__ __launch_bounds__(256) void k_phase0(const int* __restrict__ es, const int* __restrict__ ed,
                                                int* __restrict__ cnt_c, int* __restrict__ cnt_u,
                                                int E, int NBC, int NBU){
    __shared__ int hc[MAXBIN], hu[MAXBIN];
    int t = threadIdx.x;
    int base = blockIdx.x * 2048 + t;
    if (t < MAXBIN){ hc[t] = 0; hu[t] = 0; }
    __syncthreads();
    #pragma unroll
    for (int k = 0; k < 8; k++){
        int i = base + k * 256;
        if (i < E){
            int s = __builtin_nontemporal_load(&es[i]);
            int d = __builtin_nontemporal_load(&ed[i]);
            atomicAdd(&hc[d >> CSH], 1); atomicAdd(&hu[s >> USH], 1);
        }
    }
    __syncthreads();
    if (t < NBC && hc[t]) atomicAdd(&cnt_c[t], hc[t]);
    if (t < NBU && hu[t]) atomicAdd(&cnt_u[t], hu[t]);
}

__global__ void k_sbase(const int* __restrict__ cnt_c, const int* __restrict__ cnt_u,
                        int* __restrict__ base_c, int* __restrict__ cur_c,
                        int* __restrict__ base_u, int* __restrict__ cur_u,
                        int* __restrict__ off_c, int* __restrict__ off_u,
                        int NC, int NU, int NBC, int NBU, int E){
    if (threadIdx.x == 0){
        int a = 0;
        for (int b = 0; b < NBC; b++){ base_c[b] = a; cur_c[b] = a; a += cnt_c[b]; }
        a = 0;
        for (int b = 0; b < NBU; b++){ base_u[b] = a; cur_u[b] = a; a += cnt_u[b]; }
        off_c[NC] = E; off_u[NU] = E;
    }
}

__global__ __launch_bounds__(256) void k_phase1(const int* __restrict__ es, const int* __restrict__ ed,
                                                int* __restrict__ cur_c, int* __restrict__ cur_u,
                                                uint2* __restrict__ binned_c, uint2* __restrict__ binned_u,
                                                int E, int NBC, int NBU){
    __shared__ uint2 stc[2048], stu[2048];
    __shared__ int hc[MAXBIN], scc[MAXBIN], lcc[MAXBIN], gbc[MAXBIN];
    __shared__ int hu[MAXBIN], scu[MAXBIN], lcu[MAXBIN], gbu[MAXBIN];
    int t = threadIdx.x;
    int base = blockIdx.x * 2048 + t;
    int s[8], d[8];
    #pragma unroll
    for (int k = 0; k < 8; k++){
        int i = base + k * 256;
        if (i < E){ s[k] = __builtin_nontemporal_load(&es[i]); d[k] = __builtin_nontemporal_load(&ed[i]); }
    }
    if (t < MAXBIN){ hc[t] = 0; hu[t] = 0; }
    __syncthreads();
    #pragma unroll
    for (int k = 0; k < 8; k++){
        int i = base + k * 256;
        if (i < E){ atomicAdd(&hc[d[k] >> CSH], 1); atomicAdd(&hu[s[k] >> USH], 1); }
    }
    __syncthreads();
    if (t == 0){ int a = 0; for (int b = 0; b < NBC; b++){ scc[b] = a; a += hc[b]; } }
    if (t == 1){ int a = 0; for (int b = 0; b < NBU; b++){ scu[b] = a; a += hu[b]; } }
    __syncthreads();
    if (t < NBC){ lcc[t] = scc[t]; gbc[t] = atomicAdd(&cur_c[t], hc[t]); }
    if (t < NBU){ lcu[t] = scu[t]; gbu[t] = atomicAdd(&cur_u[t], hu[t]); }
    __syncthreads();
    #pragma unroll
    for (int k = 0; k < 8; k++){
        int i = base + k * 256;
        if (i < E){
            int p = atomicAdd(&lcc[d[k] >> CSH], 1); stc[p] = make_uint2((unsigned)s[k], (unsigned)d[k]);
            int q = atomicAdd(&lcu[s[k] >> USH], 1); stu[q] = make_uint2((unsigned)s[k], (unsigned)d[k]);
        }
    }
    __syncthreads();
    int nv = imin(2048, E - blockIdx.x * 2048);
    for (int i = t; i < nv; i += 256){
        uint2 e = stc[i]; int b  = (int)(e.y >> CSH); binned_c[gbc[b]  + (i - scc[b])]  = e;
        uint2 f = stu[i]; int b2 = (int)(f.x >> USH); binned_u[gbu[b2] + (i - scu[b2])] = f;
    }
}

__global__ __launch_bounds__(256) void k_p2(const uint2* __restrict__ binned_c, const uint2* __restrict__ binned_u,
                                            const int* __restrict__ cnt_c, const int* __restrict__ base_c,
                                            const int* __restrict__ cnt_u, const int* __restrict__ base_u,
                                            int* __restrict__ off_c, int* __restrict__ csr_c,
                                            int* __restrict__ off_u, int* __restrict__ csr_u,
                                            int NC, int NU, int NBC){
    __shared__ int lsh[8448];
    int t = threadIdx.x;
    if ((int)blockIdx.x < NBC){
        int b = blockIdx.x;
        int* lh  = lsh;
        int* lof = lsh + 256;
        lh[t] = 0;
        __syncthreads();
        int n = cnt_c[b], gb = base_c[b];
        const uint2* src = binned_c + gb;
        for (int i = t; i < n; i += 256) atomicAdd(&lh[src[i].y & 255], 1);
        __syncthreads();
        if (t == 0){ int a = gb; for (int c = 0; c < 256; c++){ lof[c] = a; a += lh[c]; } }
        __syncthreads();
        int gc = (b << CSH) + t;
        if (gc < NC) off_c[gc] = lof[t];
        __syncthreads();
        for (int i = t; i < n; i += 256){
            uint2 e = src[i];
            int p = atomicAdd(&lof[e.y & 255], 1);
            csr_c[p] = (int)e.x;
        }
    } else {
        int b = blockIdx.x - NBC;
        int* lh   = lsh;
        int* part = lsh + 8192;
        for (int i = t; i < 8192; i += 256) lh[i] = 0;
        __syncthreads();
        int n = cnt_u[b], gb = base_u[b];
        const uint2* src = binned_u + gb;
        for (int i = t; i < n; i += 256) atomicAdd(&lh[src[i].x & 8191], 1);
        __syncthreads();
        int ps = 0;
        #pragma unroll
        for (int j = 0; j < 32; j++) ps += lh[t * 32 + j];
        part[t] = ps;
        __syncthreads();
        if (t == 0){ int a = 0; for (int k = 0; k < 256; k++){ int tmp = part[k]; part[k] = a; a += tmp; } }
        __syncthreads();
        int a2 = gb + part[t];
        #pragma unroll
        for (int j = 0; j < 32; j++){ int idx = t * 32 + j; int tmp = lh[idx]; lh[idx] = a2; a2 += tmp; }
        __syncthreads();
        int ub = b << USH;
        for (int i = t; i < 8192; i += 256){ int gu = ub + i; if (gu < NU) off_u[gu] = lh[i]; }
        __syncthreads();
        for (int i = t; i < n; i += 256){
            uint2 e = src[i];
            int p = atomicAdd(&lh[e.x & 8191], 1);
            csr_u[p] = (int)e.y;
        }
    }
}

// ---------------- feature fusion (courses only) ----------------

__global__ void k_xc(const float* __restrict__ cx, const float* __restrict__ cemb,
                     const int* __restrict__ cidx, const float* __restrict__ Wc,
                     const float* __restrict__ bc, float* __restrict__ xc, int NC){
    int i = blockIdx.x * blockDim.x + threadIdx.x;
    if (i >= NC * 32) return;
    int c = i >> 5, f = i & 31;
    float v;
    if (f < 16) v = cemb[cidx[c] * 16 + f];
    else { int o = f - 16; v = bc[o] + cx[c * 2 + 0] * Wc[o * 2 + 0] + cx[c * 2 + 1] * Wc[o * 2 + 1]; }
    xc[i] = v;
}

// ---------------- layer 1 course side ----------------

__global__ __launch_bounds__(256) void k_course_l1(
    const int* __restrict__ off_c, const int* __restrict__ csr_c,
    const float* __restrict__ uemb, const int* __restrict__ uidx,
    const float* __restrict__ ux, const float* __restrict__ Wu, const float* __restrict__ bu,
    const float* __restrict__ Wl, const float* __restrict__ bl, const float* __restrict__ Wr,
    const float* __restrict__ Acoef /*c2r_Wl*/, const float* __restrict__ Bcoef /*c2e_Wr*/,
    const float* __restrict__ xc,
    float* __restrict__ hc2r, float* __restrict__ hcWr, int NC)
{
    __shared__ float sWlT[1024], sWrT[1024], sAT[512], sBT[512], sWu[80], sbu[16], sbl[32];
    __shared__ float part[256];
    __shared__ float agg[32], aggx[8], hc[32];
    int t = threadIdx.x;
    for (int i = t; i < 1024; i += 256){ int o = i >> 5, k = i & 31; sWlT[k * 32 + o] = Wl[i]; sWrT[k * 32 + o] = Wr[i]; }
    for (int i = t; i < 512;  i += 256){ int j = i >> 5, o = i & 31; sAT[o * 16 + j] = Acoef[i]; sBT[o * 16 + j] = Bcoef[i]; }
    if (t < 80) sWu[t] = Wu[t];
    if (t < 16) sbu[t] = bu[t];
    if (t < 32) sbl[t] = bl[t];
    __syncthreads();
    int el = t >> 5, f = t & 31;
    for (int c = blockIdx.x; c < NC; c += gridDim.x){
        int lo = off_c[c], hi = off_c[c + 1];
        float acc = 0.f;
        if (f < 21){
            int j = lo + el;
            for (; j + 24 < hi; j += 32){
                int s0 = csr_c[j], s1 = csr_c[j + 8], s2 = csr_c[j + 16], s3 = csr_c[j + 24];
                float v0, v1, v2, v3;
                if (f < 16){
                    v0 = uemb[uidx[s0] * 16 + f]; v1 = uemb[uidx[s1] * 16 + f];
                    v2 = uemb[uidx[s2] * 16 + f]; v3 = uemb[uidx[s3] * 16 + f];
                } else {
                    v0 = ux[s0 * 5 + (f - 16)]; v1 = ux[s1 * 5 + (f - 16)];
                    v2 = ux[s2 * 5 + (f - 16)]; v3 = ux[s3 * 5 + (f - 16)];
                }
                acc += (v0 + v1) + (v2 + v3);
            }
            for (; j < hi; j += 8){
                int s0 = csr_c[j];
                acc += (f < 16) ? uemb[uidx[s0] * 16 + f] : ux[s0 * 5 + (f - 16)];
            }
        }
        part[t] = acc; __syncthreads();
        float inv = 1.f / (float)imax(hi - lo, 1);
        if (el == 0 && f < 21){
            float s2 = part[f];
            #pragma unroll
            for (int k = 1; k < 8; k++) s2 += part[k * 32 + f];
            s2 *= inv;
            if (f < 16) agg[f] = s2; else aggx[f - 16] = s2;
        }
        __syncthreads();
        if (t < 16){
            float d = sbu[t];
            #pragma unroll
            for (int k = 0; k < 5; k++) d += aggx[k] * sWu[t * 5 + k];
            agg[16 + t] = d;
        }
        __syncthreads();
        if (t < 32){
            float h = sbl[t];
            for (int k = 0; k < 32; k++) h += agg[k] * sWlT[k * 32 + t] + xc[c * 32 + k] * sWrT[k * 32 + t];
            hc[t] = fmaxf(h, 0.f);
        }
        __syncthreads();
        if (t < 16){
            float a = 0.f, b = 0.f;
            for (int o = 0; o < 32; o++){ float h = hc[o]; a += h * sAT[o * 16 + t]; b += h * sBT[o * 16 + t]; }
            hc2r[c * 16 + t] = a; hcWr[c * 16 + t] = b;
        }
        __syncthreads();
    }
}

// ---------------- fused user side, MFMA version ----------------
// Per wave: 16 users. Gather (fp32) lands directly in MFMA A-fragment layout
// (lane l: user l&15, k-chunk (l>>4)*8). GEMM1 K=64: [agg32 | emb16 | ux5 | 0],
// B = [Wl | Wr[:,:16] | Wr[:,16:]@Wu | 0] (fused xu-linear), bias' = bl + Wr[:,16:]@bu.
// relu -> LDS transpose (wave-sync, no barriers) -> GEMM2 K=32 N=32 ([Acoef|Bcoef]).
__global__ __launch_bounds__(256) void k_user_mfma(
    const int* __restrict__ off_u, const int* __restrict__ csr_u,
    const float* __restrict__ xc, const float* __restrict__ hc2r,
    const float* __restrict__ uemb, const int* __restrict__ uidx, const float* __restrict__ ux,
    const float* __restrict__ Wu, const float* __restrict__ bu,
    const float* __restrict__ Wl, const float* __restrict__ bl, const float* __restrict__ Wr, // c1r
    const float* __restrict__ Acoef /*c2e_Wl*/, const float* __restrict__ Bcoef /*c2r_Wr*/,
    const float* __restrict__ bl2 /*c2r_bl*/,
    float* __restrict__ hu2e, float* __restrict__ ou, int NU)
{
    const int t = threadIdx.x;
    const int w = t >> 6, l = t & 63;
    const int ur = l & 15;   // user-row within tile == A row == C/D col
    const int kg = l >> 4;   // k-group

    // ---- per-wave constant fragments (amortized over grid-stride tiles) ----
    half8 b1[2][2], b2[2];
    float hbias[2];
    #pragma unroll
    for (int nt = 0; nt < 2; nt++){
        int o = nt * 16 + ur;
        const float* p = Wl + o * 32 + kg * 8;
        #pragma unroll
        for (int j = 0; j < 8; j++) b1[0][nt][j] = (_Float16)p[j];
        #pragma unroll
        for (int j = 0; j < 8; j++){
            int k = kg * 8 + j;
            float v;
            if (k < 16) v = Wr[o * 32 + k];
            else if (k < 21){
                int pc = k - 16; float s = 0.f;
                for (int m = 0; m < 16; m++) s += Wr[o * 32 + 16 + m] * Wu[m * 5 + pc];
                v = s;
            } else v = 0.f;
            b1[1][nt][j] = (_Float16)v;
        }
        float s = bl[o];
        for (int m = 0; m < 16; m++) s += Wr[o * 32 + 16 + m] * bu[m];
        hbias[nt] = s;
    }
    #pragma unroll
    for (int nt = 0; nt < 2; nt++){
        const float* W = nt ? Bcoef : Acoef;
        const float* p = W + ur * 32 + kg * 8;
        #pragma unroll
        for (int j = 0; j < 8; j++) b2[nt][j] = (_Float16)p[j];
    }
    const float bl2v = bl2[ur];

    __shared__ float lds_all[4][16 * 36 + 16 * 20];
    float* hl  = lds_all[w];
    float* b0l = lds_all[w] + 16 * 36;

    const int stride = gridDim.x * 64;
    for (int u0 = blockIdx.x * 64 + w * 16; u0 < NU; u0 += stride){
        int u = u0 + ur;
        int lo = 0, n = 0;
        if (u < NU){ lo = off_u[u]; n = off_u[u + 1] - lo; }
        float a[8] = {0,0,0,0,0,0,0,0};
        float p4[4] = {0,0,0,0};
        int j = 0;
        while (__any(j < n)){
            int d0 = (j     < n) ? csr_u[lo + j]     : -1;
            int d1 = (j + 1 < n) ? csr_u[lo + j + 1] : -1;
            if (d0 >= 0){
                const float4* xr = (const float4*)(xc + (size_t)d0 * 32 + kg * 8);
                float4 x0 = xr[0], x1 = xr[1];
                float4 h4 = *(const float4*)(hc2r + (size_t)d0 * 16 + kg * 4);
                a[0]+=x0.x; a[1]+=x0.y; a[2]+=x0.z; a[3]+=x0.w;
                a[4]+=x1.x; a[5]+=x1.y; a[6]+=x1.z; a[7]+=x1.w;
                p4[0]+=h4.x; p4[1]+=h4.y; p4[2]+=h4.z; p4[3]+=h4.w;
            }
            if (d1 >= 0){
                const float4* xr = (const float4*)(xc + (size_t)d1 * 32 + kg * 8);
                float4 x0 = xr[0], x1 = xr[1];
                float4 h4 = *(const float4*)(hc2r + (size_t)d1 * 16 + kg * 4);
                a[0]+=x0.x; a[1]+=x0.y; a[2]+=x0.z; a[3]+=x0.w;
                a[4]+=x1.x; a[5]+=x1.y; a[6]+=x1.z; a[7]+=x1.w;
                p4[0]+=h4.x; p4[1]+=h4.y; p4[2]+=h4.z; p4[3]+=h4.w;
            }
            j += 2;
        }
        float inv = 1.f / (float)imax(n, 1);
        half8 a1, a2;
        #pragma unroll
        for (int q = 0; q < 8; q++) a1[q] = (_Float16)(a[q] * inv);
        #pragma unroll
        for (int q = 0; q < 8; q++) a2[q] = (_Float16)0.f;
        if (u < NU){
            if (kg < 2){
                const float4* er = (const float4*)(uemb + (size_t)uidx[u] * 16 + kg * 8);
                float4 e0 = er[0], e1 = er[1];
                a2[0]=(_Float16)e0.x; a2[1]=(_Float16)e0.y; a2[2]=(_Float16)e0.z; a2[3]=(_Float16)e0.w;
                a2[4]=(_Float16)e1.x; a2[5]=(_Float16)e1.y; a2[6]=(_Float16)e1.z; a2[7]=(_Float16)e1.w;
            } else if (kg == 2){
                #pragma unroll
                for (int q = 0; q < 5; q++) a2[q] = (_Float16)ux[(size_t)u * 5 + q];
            }
        }
        // GEMM1: h[16x32]
        floatx4 c1[2];
        #pragma unroll
        for (int nt = 0; nt < 2; nt++){
            floatx4 c = {hbias[nt], hbias[nt], hbias[nt], hbias[nt]};
            c = __builtin_amdgcn_mfma_f32_16x16x32_f16(a1, b1[0][nt], c, 0, 0, 0);
            c = __builtin_amdgcn_mfma_f32_16x16x32_f16(a2, b1[1][nt], c, 0, 0, 0);
            c1[nt] = c;
        }
        // relu + LDS transpose (C layout row=kg*4+r,col=ur  ->  A layout row=ur,k=kg*8+j)
        asm volatile("s_waitcnt lgkmcnt(0)" ::: "memory");  // prev-iter LDS reads drained
        #pragma unroll
        for (int nt = 0; nt < 2; nt++)
            #pragma unroll
            for (int r = 0; r < 4; r++)
                hl[(kg * 4 + r) * 36 + nt * 16 + ur] = fmaxf(c1[nt][r], 0.f);
        #pragma unroll
        for (int q = 0; q < 4; q++) b0l[ur * 20 + kg * 4 + q] = p4[q] * inv;
        asm volatile("s_waitcnt lgkmcnt(0)" ::: "memory");  // writes visible wave-wide
        half8 ah;
        {
            const float* hp = hl + ur * 36 + kg * 8;
            #pragma unroll
            for (int q = 0; q < 8; q++) ah[q] = (_Float16)hp[q];
        }
        // GEMM2
        floatx4 c20 = {0.f, 0.f, 0.f, 0.f};
        c20 = __builtin_amdgcn_mfma_f32_16x16x32_f16(ah, b2[0], c20, 0, 0, 0);
        floatx4 c21 = {bl2v, bl2v, bl2v, bl2v};
        c21 = __builtin_amdgcn_mfma_f32_16x16x32_f16(ah, b2[1], c21, 0, 0, 0);
        #pragma unroll
        for (int r = 0; r < 4; r++){
            int urow = kg * 4 + r;
            int ug = u0 + urow;
            if (ug < NU){
                hu2e[(size_t)ug * 16 + ur] = c20[r];
                ou[(size_t)ug * 16 + ur]   = c21[r] + b0l[urow * 20 + ur];
            }
        }
    }
}

// ---------------- layer 2 course side ----------------

__global__ __launch_bounds__(256) void k_course_l2(
    const int* __restrict__ off_c, const int* __restrict__ csr_c,
    const float* __restrict__ hu2e, const float* __restrict__ bl2,
    const float* __restrict__ hcWr, float* __restrict__ oc, int NC)
{
    __shared__ float part[256];
    int t = threadIdx.x; int el = t >> 4, f = t & 15;
    for (int c = blockIdx.x; c < NC; c += gridDim.x){
        int lo = off_c[c], hi = off_c[c + 1];
        float acc = 0.f;
        int j = lo + el;
        for (; j + 48 < hi; j += 64){
            acc += hu2e[csr_c[j] * 16 + f] + hu2e[csr_c[j + 16] * 16 + f]
                 + hu2e[csr_c[j + 32] * 16 + f] + hu2e[csr_c[j + 48] * 16 + f];
        }
        for (; j < hi; j += 16) acc += hu2e[csr_c[j] * 16 + f];
        part[t] = acc; __syncthreads();
        if (el == 0){
            float s = part[f];
            #pragma unroll
            for (int k = 1; k < 16; k++) s += part[k * 16 + f];
            oc[c * 16 + f] = s / (float)imax(hi - lo, 1) + bl2[f] + hcWr[c * 16 + f];
        }
        __syncthreads();
    }
}

// ---------------- decode ----------------

__global__ void k_decode(const int* __restrict__ ls, const int* __restrict__ ld,
                         const float* __restrict__ ou, const float* __restrict__ oc,
                         float* __restrict__ out, int L){
    int gt = blockIdx.x * blockDim.x + threadIdx.x;
    int l = gt >> 2, q = gt & 3;
    if (l >= L) return;
    int a = ls[l], b = ld[l];
    float4 va = ((const float4*)(ou + (size_t)a * 16))[q];
    float4 vb = ((const float4*)(oc + (size_t)b * 16))[q];
    float s = va.x * vb.x + va.y * vb.y + va.z * vb.z + va.w * vb.w;
    s += __shfl_xor(s, 1);
    s += __shfl_xor(s, 2);
    if (q == 0) out[l] = s;
}

// ---------------- launcher ----------------

extern "C" void kernel_launch(void* const* d_in, const int* in_sizes, int n_in,
                              void* d_out, int out_size, void* d_ws, size_t ws_size,
                              hipStream_t stream)
{
    const float* user_x       = (const float*)d_in[0];
    const float* course_x     = (const float*)d_in[1];
    const float* user_embed   = (const float*)d_in[2];
    const float* course_embed = (const float*)d_in[3];
    const float* Wu = (const float*)d_in[4];
    const float* bu = (const float*)d_in[5];
    const float* Wc = (const float*)d_in[6];
    const float* bc = (const float*)d_in[7];
    const float* c1e_Wl = (const float*)d_in[8];
    const float* c1e_bl = (const float*)d_in[9];
    const float* c1e_Wr = (const float*)d_in[10];
    const float* c1r_Wl = (const float*)d_in[11];
    const float* c1r_bl = (const float*)d_in[12];
    const float* c1r_Wr = (const float*)d_in[13];
    const float* c2e_Wl = (const float*)d_in[14];
    const float* c2e_bl = (const float*)d_in[15];
    const float* c2e_Wr = (const float*)d_in[16];
    const float* c2r_Wl = (const float*)d_in[17];
    const float* c2r_bl = (const float*)d_in[18];
    const float* c2r_Wr = (const float*)d_in[19];
    const int* uidx      = (const int*)d_in[20];
    const int* cidx      = (const int*)d_in[21];
    const int* edge_src  = (const int*)d_in[22];
    const int* edge_dst  = (const int*)d_in[23];
    const int* label_src = (const int*)d_in[24];
    const int* label_dst = (const int*)d_in[25];
    const int NU = in_sizes[20], NC = in_sizes[21], E = in_sizes[22], L = in_sizes[24];
    const int NBC = (NC + 255) >> CSH;
    const int NBU = (NU + 8191) >> USH;

    char* ws = (char*)d_ws;
    size_t woff = 0;
    auto alloc = [&](size_t bytes) -> char* {
        char* p = ws + woff;
        woff = (woff + bytes + 255) & ~(size_t)255;
        return p;
    };
    int*   off_u = (int*)  alloc((size_t)(NU + 1) * 4);
    int*   off_c = (int*)  alloc((size_t)(NC + 1) * 4);
    int*   csr_c = (int*)  alloc((size_t)E * 4);
    int*   csr_u = (int*)  alloc((size_t)E * 4);
    float* xc    = (float*)alloc((size_t)NC * 32 * 4);
    float* hc2r  = (float*)alloc((size_t)NC * 16 * 4);
    float* hcWr  = (float*)alloc((size_t)NC * 16 * 4);
    float* hu2e  = (float*)alloc((size_t)NU * 16 * 4);   // binned_c aliases
    float* ou    = (float*)alloc((size_t)NU * 16 * 4);   // binned_u aliases
    float* occ   = (float*)alloc((size_t)NC * 16 * 4);
    int*   cnt_c  = (int*) alloc(MAXBIN * 4);
    int*   cnt_u  = (int*) alloc(MAXBIN * 4);
    int*   base_c = (int*) alloc(MAXBIN * 4);
    int*   base_u = (int*) alloc(MAXBIN * 4);
    int*   cur_c  = (int*) alloc(MAXBIN * 4);
    int*   cur_u  = (int*) alloc(MAXBIN * 4);
    uint2* binned_c = (uint2*)hu2e;
    uint2* binned_u = (uint2*)ou;
    (void)ws_size; (void)n_in; (void)out_size;

    int chunks = (E + 2047) / 2048;

    hipMemsetAsync(cnt_c, 0, MAXBIN * 4, stream);
    hipMemsetAsync(cnt_u, 0, MAXBIN * 4, stream);
    k_phase0<<<chunks, 256, 0, stream>>>(edge_src, edge_dst, cnt_c, cnt_u, E, NBC, NBU);
    k_sbase<<<1, 64, 0, stream>>>(cnt_c, cnt_u, base_c, cur_c, base_u, cur_u, off_c, off_u, NC, NU, NBC, NBU, E);
    k_phase1<<<chunks, 256, 0, stream>>>(edge_src, edge_dst, cur_c, cur_u, binned_c, binned_u, E, NBC, NBU);
    k_xc<<<(NC * 32 + 255) / 256, 256, 0, stream>>>(course_x, course_embed, cidx, Wc, bc, xc, NC);
    k_p2<<<NBC + NBU, 256, 0, stream>>>(binned_c, binned_u, cnt_c, base_c, cnt_u, base_u,
                                        off_c, csr_c, off_u, csr_u, NC, NU, NBC);
    k_course_l1<<<2048, 256, 0, stream>>>(off_c, csr_c, user_embed, uidx, user_x, Wu, bu,
                                          c1e_Wl, c1e_bl, c1e_Wr, c2r_Wl, c2e_Wr, xc, hc2r, hcWr, NC);
    k_user_mfma<<<1024, 256, 0, stream>>>(off_u, csr_u, xc, hc2r, user_embed, uidx, user_x,
                                          Wu, bu, c1r_Wl, c1r_bl, c1r_Wr,
                                          c2e_Wl, c2r_Wr, c2r_bl, hu2e, ou, NU);
    k_course_l2<<<1024, 256, 0, stream>>>(off_c, csr_c, hu2e, c2e_bl, hcWr, occ, NC);
    k_decode<<<(unsigned)(((size_t)L * 4 + 255) / 256), 256, 0, stream>>>(label_src, label_dst, ou, occ, (float*)d_out, L);
}

// Round 8
// 372.697 us; speedup vs baseline: 2.1703x; 1.1930x over previous
//
#include <hip/hip_runtime.h>

#define THREADS 256
#define CSH 6          // course bin shift: 64 courses/bin  -> 157 bins
#define USH 12         // user bin shift: 4096 users/bin    -> 123 bins
#define MAXBIN 192

typedef _Float16 half8 __attribute__((ext_vector_type(8)));
typedef float floatx4 __attribute__((ext_vector_type(4)));

static __device__ __forceinline__ int imax(int a, int b){ return a > b ? a : b; }
static __device__ __forceinline__ int imin(int a, int b){ return a < b ? a : b; }

// ---------------- CSR build: 2-pass LDS radix ----------------

__global__ __launch_bounds__(256) void k_phase0(const int* __restrict__ es, const int* __restrict__ ed,
                                                int* __restrict__ cnt_c, int* __restrict__ cnt_u,
                                                int E, int NBC, int NBU){
    __shared__ int hc[MAXBIN], hu[MAXBIN];
    int t = threadIdx.x;
    int base = blockIdx.x * 2048 + t;
    if (t < MAXBIN){ hc[t] = 0; hu[t] = 0; }
    __syncthreads();
    #pragma unroll
    for (int k = 0; k < 8; k++){
        int i = base + k * 256;
        if (i < E){
            int s = __builtin_nontemporal_load(&es[i]);
            int d = __builtin_nontemporal_load(&ed[i]);
            atomicAdd(&hc[d >> CSH], 1); atomicAdd(&hu[s >> USH], 1);
        }
    }
    __syncthreads();
    if (t < NBC && hc[t]) atomicAdd(&cnt_c[t], hc[t]);
    if (t < NBU && hu[t]) atomicAdd(&cnt_u[t], hu[t]);
}

__global__ void k_sbase(const int* __restrict__ cnt_c, const int* __restrict__ cnt_u,
                        int* __restrict__ base_c, int* __restrict__ cur_c,
                        int* __restrict__ base_u, int* __restrict__ cur_u,
                        int* __restrict__ off_c, int* __restrict__ off_u,
                        int NC, int NU, int NBC, int NBU, int E){
    if (threadIdx.x == 0){
        int a = 0;
        for (int b = 0; b < NBC; b++){ base_c[b] = a; cur_c[b] = a; a += cnt_c[b]; }
        a = 0;
        for (int b = 0; b < NBU; b++){ base_u[b] = a; cur_u[b] = a; a += cnt_u[b]; }
        off_c[NC] = E; off_u[NU] = E;
    }
}

__global__ __launch_bounds__(256) void k_phase1(const int* __restrict__ es, const int* __restrict__ ed,
                                                int* __restrict__ cur_c, int* __restrict__ cur_u,
                                                uint2* __restrict__ binned_c, uint2* __restrict__ binned_u,
                                                int E, int NBC, int NBU){
    __shared__ uint2 stc[2048], stu[2048];
    __shared__ int hc[MAXBIN], scc[MAXBIN], lcc[MAXBIN], gbc[MAXBIN];
    __shared__ int hu[MAXBIN], scu[MAXBIN], lcu[MAXBIN], gbu[MAXBIN];
    int t = threadIdx.x;
    int base = blockIdx.x * 2048 + t;
    int s[8], d[8];
    #pragma unroll
    for (int k = 0; k < 8; k++){
        int i = base + k * 256;
        if (i < E){ s[k] = __builtin_nontemporal_load(&es[i]); d[k] = __builtin_nontemporal_load(&ed[i]); }
    }
    if (t < MAXBIN){ hc[t] = 0; hu[t] = 0; }
    __syncthreads();
    #pragma unroll
    for (int k = 0; k < 8; k++){
        int i = base + k * 256;
        if (i < E){ atomicAdd(&hc[d[k] >> CSH], 1); atomicAdd(&hu[s[k] >> USH], 1); }
    }
    __syncthreads();
    if (t == 0){ int a = 0; for (int b = 0; b < NBC; b++){ scc[b] = a; a += hc[b]; } }
    if (t == 1){ int a = 0; for (int b = 0; b < NBU; b++){ scu[b] = a; a += hu[b]; } }
    __syncthreads();
    if (t < NBC){ lcc[t] = scc[t]; gbc[t] = atomicAdd(&cur_c[t], hc[t]); }
    if (t < NBU){ lcu[t] = scu[t]; gbu[t] = atomicAdd(&cur_u[t], hu[t]); }
    __syncthreads();
    #pragma unroll
    for (int k = 0; k < 8; k++){
        int i = base + k * 256;
        if (i < E){
            int p = atomicAdd(&lcc[d[k] >> CSH], 1); stc[p] = make_uint2((unsigned)s[k], (unsigned)d[k]);
            int q = atomicAdd(&lcu[s[k] >> USH], 1); stu[q] = make_uint2((unsigned)s[k], (unsigned)d[k]);
        }
    }
    __syncthreads();
    int nv = imin(2048, E - blockIdx.x * 2048);
    for (int i = t; i < nv; i += 256){
        uint2 e = stc[i]; int b  = (int)(e.y >> CSH); binned_c[gbc[b]  + (i - scc[b])]  = e;
        uint2 f = stu[i]; int b2 = (int)(f.x >> USH); binned_u[gbu[b2] + (i - scu[b2])] = f;
    }
}

// Phase 2: one block per bin, 1024 threads. Exact per-node CSR inside an
// L2-resident window. LDS hist + parallel scan yields off_c/off_u directly.
__global__ __launch_bounds__(1024) void k_p2(const uint2* __restrict__ binned_c, const uint2* __restrict__ binned_u,
                                             const int* __restrict__ cnt_c, const int* __restrict__ base_c,
                                             const int* __restrict__ cnt_u, const int* __restrict__ base_u,
                                             int* __restrict__ off_c, int* __restrict__ csr_c,
                                             int* __restrict__ off_u, int* __restrict__ csr_u,
                                             int NC, int NU, int NBC){
    __shared__ int lsh[5120];
    int t = threadIdx.x;
    const int CB = 1 << CSH;   // 64 courses/bin
    if ((int)blockIdx.x < NBC){
        int b = blockIdx.x;
        int* lh  = lsh;        // [CB]
        int* lof = lsh + CB;   // [CB]
        if (t < CB) lh[t] = 0;
        __syncthreads();
        int n = cnt_c[b], gb = base_c[b];
        const uint2* src = binned_c + gb;
        for (int i = t; i < n; i += 1024) atomicAdd(&lh[src[i].y & (CB - 1)], 1);
        __syncthreads();
        if (t == 0){ int a = gb; for (int c = 0; c < CB; c++){ lof[c] = a; a += lh[c]; } }
        __syncthreads();
        int gc = (b << CSH) + t;
        if (t < CB && gc < NC) off_c[gc] = lof[t];
        __syncthreads();
        for (int i = t; i < n; i += 1024){
            uint2 e = src[i];
            int p = atomicAdd(&lof[e.y & (CB - 1)], 1);
            csr_c[p] = (int)e.x;
        }
    } else {
        int b = blockIdx.x - NBC;
        const int UB = 1 << USH;  // 4096 users/bin
        int* lh   = lsh;          // [4096]
        int* part = lsh + UB;     // [1024]
        for (int i = t; i < UB; i += 1024) lh[i] = 0;
        __syncthreads();
        int n = cnt_u[b], gb = base_u[b];
        const uint2* src = binned_u + gb;
        for (int i = t; i < n; i += 1024) atomicAdd(&lh[src[i].x & (UB - 1)], 1);
        __syncthreads();
        int ps = lh[t * 4] + lh[t * 4 + 1] + lh[t * 4 + 2] + lh[t * 4 + 3];
        part[t] = ps;
        __syncthreads();
        for (int dd = 1; dd < 1024; dd <<= 1){       // Hillis-Steele inclusive scan
            int v = (t >= dd) ? part[t - dd] : 0;
            __syncthreads();
            if (t >= dd) part[t] += v;
            __syncthreads();
        }
        int a2 = gb + (t ? part[t - 1] : 0);
        #pragma unroll
        for (int j = 0; j < 4; j++){ int idx = t * 4 + j; int tmp = lh[idx]; lh[idx] = a2; a2 += tmp; }
        __syncthreads();
        int ub = b << USH;
        for (int i = t; i < UB; i += 1024){ int gu = ub + i; if (gu < NU) off_u[gu] = lh[i]; }
        __syncthreads();
        for (int i = t; i < n; i += 1024){
            uint2 e = src[i];
            int p = atomicAdd(&lh[e.x & (UB - 1)], 1);
            csr_u[p] = (int)e.y;
        }
    }
}

// ---------------- feature fusion (courses only) ----------------

__global__ void k_xc(const float* __restrict__ cx, const float* __restrict__ cemb,
                     const int* __restrict__ cidx, const float* __restrict__ Wc,
                     const float* __restrict__ bc, float* __restrict__ xc, int NC){
    int i = blockIdx.x * blockDim.x + threadIdx.x;
    if (i >= NC * 32) return;
    int c = i >> 5, f = i & 31;
    float v;
    if (f < 16) v = cemb[cidx[c] * 16 + f];
    else { int o = f - 16; v = bc[o] + cx[c * 2 + 0] * Wc[o * 2 + 0] + cx[c * 2 + 1] * Wc[o * 2 + 1]; }
    xc[i] = v;
}

// ---------------- layer 1 course side ----------------

__global__ __launch_bounds__(256) void k_course_l1(
    const int* __restrict__ off_c, const int* __restrict__ csr_c,
    const float* __restrict__ uemb, const int* __restrict__ uidx,
    const float* __restrict__ ux, const float* __restrict__ Wu, const float* __restrict__ bu,
    const float* __restrict__ Wl, const float* __restrict__ bl, const float* __restrict__ Wr,
    const float* __restrict__ Acoef /*c2r_Wl*/, const float* __restrict__ Bcoef /*c2e_Wr*/,
    const float* __restrict__ xc,
    float* __restrict__ hc2r, float* __restrict__ hcWr, int NC)
{
    __shared__ float sWlT[1024], sWrT[1024], sAT[512], sBT[512], sWu[80], sbu[16], sbl[32];
    __shared__ float part[256];
    __shared__ float agg[32], aggx[8], hc[32];
    int t = threadIdx.x;
    for (int i = t; i < 1024; i += 256){ int o = i >> 5, k = i & 31; sWlT[k * 32 + o] = Wl[i]; sWrT[k * 32 + o] = Wr[i]; }
    for (int i = t; i < 512;  i += 256){ int j = i >> 5, o = i & 31; sAT[o * 16 + j] = Acoef[i]; sBT[o * 16 + j] = Bcoef[i]; }
    if (t < 80) sWu[t] = Wu[t];
    if (t < 16) sbu[t] = bu[t];
    if (t < 32) sbl[t] = bl[t];
    __syncthreads();
    int el = t >> 5, f = t & 31;
    for (int c = blockIdx.x; c < NC; c += gridDim.x){
        int lo = off_c[c], hi = off_c[c + 1];
        float acc = 0.f;
        if (f < 21){
            int j = lo + el;
            for (; j + 24 < hi; j += 32){
                int s0 = csr_c[j], s1 = csr_c[j + 8], s2 = csr_c[j + 16], s3 = csr_c[j + 24];
                float v0, v1, v2, v3;
                if (f < 16){
                    v0 = uemb[uidx[s0] * 16 + f]; v1 = uemb[uidx[s1] * 16 + f];
                    v2 = uemb[uidx[s2] * 16 + f]; v3 = uemb[uidx[s3] * 16 + f];
                } else {
                    v0 = ux[s0 * 5 + (f - 16)]; v1 = ux[s1 * 5 + (f - 16)];
                    v2 = ux[s2 * 5 + (f - 16)]; v3 = ux[s3 * 5 + (f - 16)];
                }
                acc += (v0 + v1) + (v2 + v3);
            }
            for (; j < hi; j += 8){
                int s0 = csr_c[j];
                acc += (f < 16) ? uemb[uidx[s0] * 16 + f] : ux[s0 * 5 + (f - 16)];
            }
        }
        part[t] = acc; __syncthreads();
        float inv = 1.f / (float)imax(hi - lo, 1);
        if (el == 0 && f < 21){
            float s2 = part[f];
            #pragma unroll
            for (int k = 1; k < 8; k++) s2 += part[k * 32 + f];
            s2 *= inv;
            if (f < 16) agg[f] = s2; else aggx[f - 16] = s2;
        }
        __syncthreads();
        if (t < 16){
            float d = sbu[t];
            #pragma unroll
            for (int k = 0; k < 5; k++) d += aggx[k] * sWu[t * 5 + k];
            agg[16 + t] = d;
        }
        __syncthreads();
        if (t < 32){
            float h = sbl[t];
            for (int k = 0; k < 32; k++) h += agg[k] * sWlT[k * 32 + t] + xc[c * 32 + k] * sWrT[k * 32 + t];
            hc[t] = fmaxf(h, 0.f);
        }
        __syncthreads();
        if (t < 16){
            float a = 0.f, b = 0.f;
            for (int o = 0; o < 32; o++){ float h = hc[o]; a += h * sAT[o * 16 + t]; b += h * sBT[o * 16 + t]; }
            hc2r[c * 16 + t] = a; hcWr[c * 16 + t] = b;
        }
        __syncthreads();
    }
}

// ---------------- fused user side, MFMA version ----------------

__global__ __launch_bounds__(256) void k_user_mfma(
    const int* __restrict__ off_u, const int* __restrict__ csr_u,
    const float* __restrict__ xc, const float* __restrict__ hc2r,
    const float* __restrict__ uemb, const int* __restrict__ uidx, const float* __restrict__ ux,
    const float* __restrict__ Wu, const float* __restrict__ bu,
    const float* __restrict__ Wl, const float* __restrict__ bl, const float* __restrict__ Wr, // c1r
    const float* __restrict__ Acoef /*c2e_Wl*/, const float* __restrict__ Bcoef /*c2r_Wr*/,
    const float* __restrict__ bl2 /*c2r_bl*/,
    float* __restrict__ hu2e, float* __restrict__ ou, int NU)
{
    const int t = threadIdx.x;
    const int w = t >> 6, l = t & 63;
    const int ur = l & 15;
    const int kg = l >> 4;

    half8 b1[2][2], b2[2];
    float hbias[2];
    #pragma unroll
    for (int nt = 0; nt < 2; nt++){
        int o = nt * 16 + ur;
        const float* p = Wl + o * 32 + kg * 8;
        #pragma unroll
        for (int j = 0; j < 8; j++) b1[0][nt][j] = (_Float16)p[j];
        #pragma unroll
        for (int j = 0; j < 8; j++){
            int k = kg * 8 + j;
            float v;
            if (k < 16) v = Wr[o * 32 + k];
            else if (k < 21){
                int pc = k - 16; float s = 0.f;
                for (int m = 0; m < 16; m++) s += Wr[o * 32 + 16 + m] * Wu[m * 5 + pc];
                v = s;
            } else v = 0.f;
            b1[1][nt][j] = (_Float16)v;
        }
        float s = bl[o];
        for (int m = 0; m < 16; m++) s += Wr[o * 32 + 16 + m] * bu[m];
        hbias[nt] = s;
    }
    #pragma unroll
    for (int nt = 0; nt < 2; nt++){
        const float* W = nt ? Bcoef : Acoef;
        const float* p = W + ur * 32 + kg * 8;
        #pragma unroll
        for (int j = 0; j < 8; j++) b2[nt][j] = (_Float16)p[j];
    }
    const float bl2v = bl2[ur];

    __shared__ float lds_all[4][16 * 36 + 16 * 20];
    float* hl  = lds_all[w];
    float* b0l = lds_all[w] + 16 * 36;

    const int stride = gridDim.x * 64;
    for (int u0 = blockIdx.x * 64 + w * 16; u0 < NU; u0 += stride){
        int u = u0 + ur;
        int lo = 0, n = 0;
        if (u < NU){ lo = off_u[u]; n = off_u[u + 1] - lo; }
        float a[8] = {0,0,0,0,0,0,0,0};
        float p4[4] = {0,0,0,0};
        int j = 0;
        while (__any(j < n)){
            int d0 = (j     < n) ? csr_u[lo + j]     : -1;
            int d1 = (j + 1 < n) ? csr_u[lo + j + 1] : -1;
            if (d0 >= 0){
                const float4* xr = (const float4*)(xc + (size_t)d0 * 32 + kg * 8);
                float4 x0 = xr[0], x1 = xr[1];
                float4 h4 = *(const float4*)(hc2r + (size_t)d0 * 16 + kg * 4);
                a[0]+=x0.x; a[1]+=x0.y; a[2]+=x0.z; a[3]+=x0.w;
                a[4]+=x1.x; a[5]+=x1.y; a[6]+=x1.z; a[7]+=x1.w;
                p4[0]+=h4.x; p4[1]+=h4.y; p4[2]+=h4.z; p4[3]+=h4.w;
            }
            if (d1 >= 0){
                const float4* xr = (const float4*)(xc + (size_t)d1 * 32 + kg * 8);
                float4 x0 = xr[0], x1 = xr[1];
                float4 h4 = *(const float4*)(hc2r + (size_t)d1 * 16 + kg * 4);
                a[0]+=x0.x; a[1]+=x0.y; a[2]+=x0.z; a[3]+=x0.w;
                a[4]+=x1.x; a[5]+=x1.y; a[6]+=x1.z; a[7]+=x1.w;
                p4[0]+=h4.x; p4[1]+=h4.y; p4[2]+=h4.z; p4[3]+=h4.w;
            }
            j += 2;
        }
        float inv = 1.f / (float)imax(n, 1);
        half8 a1, a2;
        #pragma unroll
        for (int q = 0; q < 8; q++) a1[q] = (_Float16)(a[q] * inv);
        #pragma unroll
        for (int q = 0; q < 8; q++) a2[q] = (_Float16)0.f;
        if (u < NU){
            if (kg < 2){
                const float4* er = (const float4*)(uemb + (size_t)uidx[u] * 16 + kg * 8);
                float4 e0 = er[0], e1 = er[1];
                a2[0]=(_Float16)e0.x; a2[1]=(_Float16)e0.y; a2[2]=(_Float16)e0.z; a2[3]=(_Float16)e0.w;
                a2[4]=(_Float16)e1.x; a2[5]=(_Float16)e1.y; a2[6]=(_Float16)e1.z; a2[7]=(_Float16)e1.w;
            } else if (kg == 2){
                #pragma unroll
                for (int q = 0; q < 5; q++) a2[q] = (_Float16)ux[(size_t)u * 5 + q];
            }
        }
        floatx4 c1[2];
        #pragma unroll
        for (int nt = 0; nt < 2; nt++){
            floatx4 c = {hbias[nt], hbias[nt], hbias[nt], hbias[nt]};
            c = __builtin_amdgcn_mfma_f32_16x16x32_f16(a1, b1[0][nt], c, 0, 0, 0);
            c = __builtin_amdgcn_mfma_f32_16x16x32_f16(a2, b1[1][nt], c, 0, 0, 0);
            c1[nt] = c;
        }
        asm volatile("s_waitcnt lgkmcnt(0)" ::: "memory");
        #pragma unroll
        for (int nt = 0; nt < 2; nt++)
            #pragma unroll
            for (int r = 0; r < 4; r++)
                hl[(kg * 4 + r) * 36 + nt * 16 + ur] = fmaxf(c1[nt][r], 0.f);
        #pragma unroll
        for (int q = 0; q < 4; q++) b0l[ur * 20 + kg * 4 + q] = p4[q] * inv;
        asm volatile("s_waitcnt lgkmcnt(0)" ::: "memory");
        half8 ah;
        {
            const float* hp = hl + ur * 36 + kg * 8;
            #pragma unroll
            for (int q = 0; q < 8; q++) ah[q] = (_Float16)hp[q];
        }
        floatx4 c20 = {0.f, 0.f, 0.f, 0.f};
        c20 = __builtin_amdgcn_mfma_f32_16x16x32_f16(ah, b2[0], c20, 0, 0, 0);
        floatx4 c21 = {bl2v, bl2v, bl2v, bl2v};
        c21 = __builtin_amdgcn_mfma_f32_16x16x32_f16(ah, b2[1], c21, 0, 0, 0);
        #pragma unroll
        for (int r = 0; r < 4; r++){
            int urow = kg * 4 + r;
            int ug = u0 + urow;
            if (ug < NU){
                hu2e[(size_t)ug * 16 + ur] = c20[r];
                ou[(size_t)ug * 16 + ur]   = c21[r] + b0l[urow * 20 + ur];
            }
        }
    }
}

// ---------------- layer 2 course side ----------------

__global__ __launch_bounds__(256) void k_course_l2(
    const int* __restrict__ off_c, const int* __restrict__ csr_c,
    const float* __restrict__ hu2e, const float* __restrict__ bl2,
    const float* __restrict__ hcWr, float* __restrict__ oc, int NC)
{
    __shared__ float part[256];
    int t = threadIdx.x; int el = t >> 4, f = t & 15;
    for (int c = blockIdx.x; c < NC; c += gridDim.x){
        int lo = off_c[c], hi = off_c[c + 1];
        float acc = 0.f;
        int j = lo + el;
        for (; j + 48 < hi; j += 64){
            acc += hu2e[csr_c[j] * 16 + f] + hu2e[csr_c[j + 16] * 16 + f]
                 + hu2e[csr_c[j + 32] * 16 + f] + hu2e[csr_c[j + 48] * 16 + f];
        }
        for (; j < hi; j += 16) acc += hu2e[csr_c[j] * 16 + f];
        part[t] = acc; __syncthreads();
        if (el == 0){
            float s = part[f];
            #pragma unroll
            for (int k = 1; k < 16; k++) s += part[k * 16 + f];
            oc[c * 16 + f] = s / (float)imax(hi - lo, 1) + bl2[f] + hcWr[c * 16 + f];
        }
        __syncthreads();
    }
}

// ---------------- decode ----------------

__global__ void k_decode(const int* __restrict__ ls, const int* __restrict__ ld,
                         const float* __restrict__ ou, const float* __restrict__ oc,
                         float* __restrict__ out, int L){
    int gt = blockIdx.x * blockDim.x + threadIdx.x;
    int l = gt >> 2, q = gt & 3;
    if (l >= L) return;
    int a = ls[l], b = ld[l];
    float4 va = ((const float4*)(ou + (size_t)a * 16))[q];
    float4 vb = ((const float4*)(oc + (size_t)b * 16))[q];
    float s = va.x * vb.x + va.y * vb.y + va.z * vb.z + va.w * vb.w;
    s += __shfl_xor(s, 1);
    s += __shfl_xor(s, 2);
    if (q == 0) out[l] = s;
}

// ---------------- launcher ----------------

extern "C" void kernel_launch(void* const* d_in, const int* in_sizes, int n_in,
                              void* d_out, int out_size, void* d_ws, size_t ws_size,
                              hipStream_t stream)
{
    const float* user_x       = (const float*)d_in[0];
    const float* course_x     = (const float*)d_in[1];
    const float* user_embed   = (const float*)d_in[2];
    const float* course_embed = (const float*)d_in[3];
    const float* Wu = (const float*)d_in[4];
    const float* bu = (const float*)d_in[5];
    const float* Wc = (const float*)d_in[6];
    const float* bc = (const float*)d_in[7];
    const float* c1e_Wl = (const float*)d_in[8];
    const float* c1e_bl = (const float*)d_in[9];
    const float* c1e_Wr = (const float*)d_in[10];
    const float* c1r_Wl = (const float*)d_in[11];
    const float* c1r_bl = (const float*)d_in[12];
    const float* c1r_Wr = (const float*)d_in[13];
    const float* c2e_Wl = (const float*)d_in[14];
    const float* c2e_bl = (const float*)d_in[15];
    const float* c2e_Wr = (const float*)d_in[16];
    const float* c2r_Wl = (const float*)d_in[17];
    const float* c2r_bl = (const float*)d_in[18];
    const float* c2r_Wr = (const float*)d_in[19];
    const int* uidx      = (const int*)d_in[20];
    const int* cidx      = (const int*)d_in[21];
    const int* edge_src  = (const int*)d_in[22];
    const int* edge_dst  = (const int*)d_in[23];
    const int* label_src = (const int*)d_in[24];
    const int* label_dst = (const int*)d_in[25];
    const int NU = in_sizes[20], NC = in_sizes[21], E = in_sizes[22], L = in_sizes[24];
    const int NBC = (NC + (1 << CSH) - 1) >> CSH;   // 157
    const int NBU = (NU + (1 << USH) - 1) >> USH;   // 123

    char* ws = (char*)d_ws;
    size_t woff = 0;
    auto alloc = [&](size_t bytes) -> char* {
        char* p = ws + woff;
        woff = (woff + bytes + 255) & ~(size_t)255;
        return p;
    };
    int*   off_u = (int*)  alloc((size_t)(NU + 1) * 4);
    int*   off_c = (int*)  alloc((size_t)(NC + 1) * 4);
    int*   csr_c = (int*)  alloc((size_t)E * 4);
    int*   csr_u = (int*)  alloc((size_t)E * 4);
    float* xc    = (float*)alloc((size_t)NC * 32 * 4);
    float* hc2r  = (float*)alloc((size_t)NC * 16 * 4);
    float* hcWr  = (float*)alloc((size_t)NC * 16 * 4);
    float* hu2e  = (float*)alloc((size_t)NU * 16 * 4);   // binned_c aliases
    float* ou    = (float*)alloc((size_t)NU * 16 * 4);   // binned_u aliases
    float* occ   = (float*)alloc((size_t)NC * 16 * 4);
    int*   cnt_c  = (int*) alloc(MAXBIN * 4);
    int*   cnt_u  = (int*) alloc(MAXBIN * 4);
    int*   base_c = (int*) alloc(MAXBIN * 4);
    int*   base_u = (int*) alloc(MAXBIN * 4);
    int*   cur_c  = (int*) alloc(MAXBIN * 4);
    int*   cur_u  = (int*) alloc(MAXBIN * 4);
    uint2* binned_c = (uint2*)hu2e;
    uint2* binned_u = (uint2*)ou;
    (void)ws_size; (void)n_in; (void)out_size;

    int chunks = (E + 2047) / 2048;

    hipMemsetAsync(cnt_c, 0, MAXBIN * 4, stream);
    hipMemsetAsync(cnt_u, 0, MAXBIN * 4, stream);
    k_phase0<<<chunks, 256, 0, stream>>>(edge_src, edge_dst, cnt_c, cnt_u, E, NBC, NBU);
    k_sbase<<<1, 64, 0, stream>>>(cnt_c, cnt_u, base_c, cur_c, base_u, cur_u, off_c, off_u, NC, NU, NBC, NBU, E);
    k_phase1<<<chunks, 256, 0, stream>>>(edge_src, edge_dst, cur_c, cur_u, binned_c, binned_u, E, NBC, NBU);
    k_xc<<<(NC * 32 + 255) / 256, 256, 0, stream>>>(course_x, course_embed, cidx, Wc, bc, xc, NC);
    k_p2<<<NBC + NBU, 1024, 0, stream>>>(binned_c, binned_u, cnt_c, base_c, cnt_u, base_u,
                                         off_c, csr_c, off_u, csr_u, NC, NU, NBC);
    k_course_l1<<<2048, 256, 0, stream>>>(off_c, csr_c, user_embed, uidx, user_x, Wu, bu,
                                          c1e_Wl, c1e_bl, c1e_Wr, c2r_Wl, c2e_Wr, xc, hc2r, hcWr, NC);
    k_user_mfma<<<1024, 256, 0, stream>>>(off_u, csr_u, xc, hc2r, user_embed, uidx, user_x,
                                          Wu, bu, c1r_Wl, c1r_bl, c1r_Wr,
                                          c2e_Wl, c2r_Wr, c2r_bl, hu2e, ou, NU);
    k_course_l2<<<1024, 256, 0, stream>>>(off_c, csr_c, hu2e, c2e_bl, hcWr, occ, NC);
    k_decode<<<(unsigned)(((size_t)L * 4 + 255) / 256), 256, 0, stream>>>(label_src, label_dst, ou, occ, (float*)d_out, L);
}

// Round 9
// 352.564 us; speedup vs baseline: 2.2942x; 1.0571x over previous
//
#include <hip/hip_runtime.h>

#define THREADS 256
#define CSH 6          // course bin shift: 64 courses/bin  -> 157 bins
#define USH 12         // user bin shift: 4096 users/bin    -> 123 bins
#define MAXBIN 192

typedef _Float16 half8 __attribute__((ext_vector_type(8)));
typedef float floatx4 __attribute__((ext_vector_type(4)));

static __device__ __forceinline__ int imax(int a, int b){ return a > b ? a : b; }
static __device__ __forceinline__ int imin(int a, int b){ return a < b ? a : b; }

// ---------------- CSR build: 2-pass LDS radix ----------------

__global__ __launch_bounds__(256) void k_phase0(const int* __restrict__ es, const int* __restrict__ ed,
                                                int* __restrict__ cnt_c, int* __restrict__ cnt_u,
                                                int E, int NBC, int NBU){
    __shared__ int hc[MAXBIN], hu[MAXBIN];
    int t = threadIdx.x;
    int base = blockIdx.x * 2048 + t;
    if (t < MAXBIN){ hc[t] = 0; hu[t] = 0; }
    __syncthreads();
    #pragma unroll
    for (int k = 0; k < 8; k++){
        int i = base + k * 256;
        if (i < E){
            int s = __builtin_nontemporal_load(&es[i]);
            int d = __builtin_nontemporal_load(&ed[i]);
            atomicAdd(&hc[d >> CSH], 1); atomicAdd(&hu[s >> USH], 1);
        }
    }
    __syncthreads();
    if (t < NBC && hc[t]) atomicAdd(&cnt_c[t], hc[t]);
    if (t < NBU && hu[t]) atomicAdd(&cnt_u[t], hu[t]);
}

__global__ void k_sbase(const int* __restrict__ cnt_c, const int* __restrict__ cnt_u,
                        int* __restrict__ base_c, int* __restrict__ cur_c,
                        int* __restrict__ base_u, int* __restrict__ cur_u,
                        int* __restrict__ off_c, int* __restrict__ off_u,
                        int NC, int NU, int NBC, int NBU, int E){
    if (threadIdx.x == 0){
        int a = 0;
        for (int b = 0; b < NBC; b++){ base_c[b] = a; cur_c[b] = a; a += cnt_c[b]; }
        a = 0;
        for (int b = 0; b < NBU; b++){ base_u[b] = a; cur_u[b] = a; a += cnt_u[b]; }
        off_c[NC] = E; off_u[NU] = E;
    }
}

__global__ __launch_bounds__(256) void k_phase1(const int* __restrict__ es, const int* __restrict__ ed,
                                                int* __restrict__ cur_c, int* __restrict__ cur_u,
                                                uint2* __restrict__ binned_c, uint2* __restrict__ binned_u,
                                                int E, int NBC, int NBU){
    __shared__ uint2 stc[2048], stu[2048];
    __shared__ int hc[MAXBIN], scc[MAXBIN], lcc[MAXBIN], gbc[MAXBIN];
    __shared__ int hu[MAXBIN], scu[MAXBIN], lcu[MAXBIN], gbu[MAXBIN];
    int t = threadIdx.x;
    int base = blockIdx.x * 2048 + t;
    int s[8], d[8];
    #pragma unroll
    for (int k = 0; k < 8; k++){
        int i = base + k * 256;
        if (i < E){ s[k] = __builtin_nontemporal_load(&es[i]); d[k] = __builtin_nontemporal_load(&ed[i]); }
    }
    if (t < MAXBIN){ hc[t] = 0; hu[t] = 0; }
    __syncthreads();
    #pragma unroll
    for (int k = 0; k < 8; k++){
        int i = base + k * 256;
        if (i < E){ atomicAdd(&hc[d[k] >> CSH], 1); atomicAdd(&hu[s[k] >> USH], 1); }
    }
    __syncthreads();
    if (t == 0){ int a = 0; for (int b = 0; b < NBC; b++){ scc[b] = a; a += hc[b]; } }
    if (t == 1){ int a = 0; for (int b = 0; b < NBU; b++){ scu[b] = a; a += hu[b]; } }
    __syncthreads();
    if (t < NBC){ lcc[t] = scc[t]; gbc[t] = atomicAdd(&cur_c[t], hc[t]); }
    if (t < NBU){ lcu[t] = scu[t]; gbu[t] = atomicAdd(&cur_u[t], hu[t]); }
    __syncthreads();
    #pragma unroll
    for (int k = 0; k < 8; k++){
        int i = base + k * 256;
        if (i < E){
            int p = atomicAdd(&lcc[d[k] >> CSH], 1); stc[p] = make_uint2((unsigned)s[k], (unsigned)d[k]);
            int q = atomicAdd(&lcu[s[k] >> USH], 1); stu[q] = make_uint2((unsigned)s[k], (unsigned)d[k]);
        }
    }
    __syncthreads();
    int nv = imin(2048, E - blockIdx.x * 2048);
    for (int i = t; i < nv; i += 256){
        uint2 e = stc[i]; int b  = (int)(e.y >> CSH); binned_c[gbc[b]  + (i - scc[b])]  = e;
        uint2 f = stu[i]; int b2 = (int)(f.x >> USH); binned_u[gbu[b2] + (i - scu[b2])] = f;
    }
}

__global__ __launch_bounds__(1024) void k_p2(const uint2* __restrict__ binned_c, const uint2* __restrict__ binned_u,
                                             const int* __restrict__ cnt_c, const int* __restrict__ base_c,
                                             const int* __restrict__ cnt_u, const int* __restrict__ base_u,
                                             int* __restrict__ off_c, int* __restrict__ csr_c,
                                             int* __restrict__ off_u, int* __restrict__ csr_u,
                                             int NC, int NU, int NBC){
    __shared__ int lsh[5120];
    int t = threadIdx.x;
    const int CB = 1 << CSH;
    if ((int)blockIdx.x < NBC){
        int b = blockIdx.x;
        int* lh  = lsh;
        int* lof = lsh + CB;
        if (t < CB) lh[t] = 0;
        __syncthreads();
        int n = cnt_c[b], gb = base_c[b];
        const uint2* src = binned_c + gb;
        for (int i = t; i < n; i += 1024) atomicAdd(&lh[src[i].y & (CB - 1)], 1);
        __syncthreads();
        if (t == 0){ int a = gb; for (int c = 0; c < CB; c++){ lof[c] = a; a += lh[c]; } }
        __syncthreads();
        int gc = (b << CSH) + t;
        if (t < CB && gc < NC) off_c[gc] = lof[t];
        __syncthreads();
        for (int i = t; i < n; i += 1024){
            uint2 e = src[i];
            int p = atomicAdd(&lof[e.y & (CB - 1)], 1);
            csr_c[p] = (int)e.x;
        }
    } else {
        int b = blockIdx.x - NBC;
        const int UB = 1 << USH;
        int* lh   = lsh;
        int* part = lsh + UB;
        for (int i = t; i < UB; i += 1024) lh[i] = 0;
        __syncthreads();
        int n = cnt_u[b], gb = base_u[b];
        const uint2* src = binned_u + gb;
        for (int i = t; i < n; i += 1024) atomicAdd(&lh[src[i].x & (UB - 1)], 1);
        __syncthreads();
        int ps = lh[t * 4] + lh[t * 4 + 1] + lh[t * 4 + 2] + lh[t * 4 + 3];
        part[t] = ps;
        __syncthreads();
        for (int dd = 1; dd < 1024; dd <<= 1){
            int v = (t >= dd) ? part[t - dd] : 0;
            __syncthreads();
            if (t >= dd) part[t] += v;
            __syncthreads();
        }
        int a2 = gb + (t ? part[t - 1] : 0);
        #pragma unroll
        for (int j = 0; j < 4; j++){ int idx = t * 4 + j; int tmp = lh[idx]; lh[idx] = a2; a2 += tmp; }
        __syncthreads();
        int ub = b << USH;
        for (int i = t; i < UB; i += 1024){ int gu = ub + i; if (gu < NU) off_u[gu] = lh[i]; }
        __syncthreads();
        for (int i = t; i < n; i += 1024){
            uint2 e = src[i];
            int p = atomicAdd(&lh[e.x & (UB - 1)], 1);
            csr_u[p] = (int)e.y;
        }
    }
}

// ---------------- packed fp16 user features: [emb16 | ux5 | 0..] = 64B/row ----------------

__global__ __launch_bounds__(256) void k_xu16(const float* __restrict__ uemb, const int* __restrict__ uidx,
                                              const float* __restrict__ ux, _Float16* __restrict__ xu16, int NU){
    int u = blockIdx.x * blockDim.x + threadIdx.x;
    if (u >= NU) return;
    const float4* er = (const float4*)(uemb + (size_t)uidx[u] * 16);
    float4 e0 = er[0], e1 = er[1], e2 = er[2], e3 = er[3];
    _Float16 h[32];
    h[0]=(_Float16)e0.x; h[1]=(_Float16)e0.y; h[2]=(_Float16)e0.z; h[3]=(_Float16)e0.w;
    h[4]=(_Float16)e1.x; h[5]=(_Float16)e1.y; h[6]=(_Float16)e1.z; h[7]=(_Float16)e1.w;
    h[8]=(_Float16)e2.x; h[9]=(_Float16)e2.y; h[10]=(_Float16)e2.z; h[11]=(_Float16)e2.w;
    h[12]=(_Float16)e3.x; h[13]=(_Float16)e3.y; h[14]=(_Float16)e3.z; h[15]=(_Float16)e3.w;
    const float* xr = ux + (size_t)u * 5;
    h[16]=(_Float16)xr[0]; h[17]=(_Float16)xr[1]; h[18]=(_Float16)xr[2]; h[19]=(_Float16)xr[3]; h[20]=(_Float16)xr[4];
    #pragma unroll
    for (int q = 21; q < 32; q++) h[q] = (_Float16)0.f;
    float4* out = (float4*)(xu16 + (size_t)u * 32);
    const float4* hv = (const float4*)h;
    out[0] = hv[0]; out[1] = hv[1]; out[2] = hv[2]; out[3] = hv[3];
}

// ---------------- feature fusion (courses only) ----------------

__global__ void k_xc(const float* __restrict__ cx, const float* __restrict__ cemb,
                     const int* __restrict__ cidx, const float* __restrict__ Wc,
                     const float* __restrict__ bc, float* __restrict__ xc, int NC){
    int i = blockIdx.x * blockDim.x + threadIdx.x;
    if (i >= NC * 32) return;
    int c = i >> 5, f = i & 31;
    float v;
    if (f < 16) v = cemb[cidx[c] * 16 + f];
    else { int o = f - 16; v = bc[o] + cx[c * 2 + 0] * Wc[o * 2 + 0] + cx[c * 2 + 1] * Wc[o * 2 + 1]; }
    xc[i] = v;
}

// ---------------- layer 1 course side ----------------
// gathers packed xu16 rows (one 64B line per edge); linearity epilogue unchanged.

__global__ __launch_bounds__(256) void k_course_l1(
    const int* __restrict__ off_c, const int* __restrict__ csr_c,
    const _Float16* __restrict__ xu16,
    const float* __restrict__ Wu, const float* __restrict__ bu,
    const float* __restrict__ Wl, const float* __restrict__ bl, const float* __restrict__ Wr,
    const float* __restrict__ Acoef /*c2r_Wl*/, const float* __restrict__ Bcoef /*c2e_Wr*/,
    const float* __restrict__ xc,
    float* __restrict__ hc2r, float* __restrict__ hcWr, int NC)
{
    __shared__ float sWlT[1024], sWrT[1024], sAT[512], sBT[512], sWu[80], sbu[16], sbl[32];
    __shared__ float part[256];
    __shared__ float agg[32], aggx[8], hc[32];
    int t = threadIdx.x;
    for (int i = t; i < 1024; i += 256){ int o = i >> 5, k = i & 31; sWlT[k * 32 + o] = Wl[i]; sWrT[k * 32 + o] = Wr[i]; }
    for (int i = t; i < 512;  i += 256){ int j = i >> 5, o = i & 31; sAT[o * 16 + j] = Acoef[i]; sBT[o * 16 + j] = Bcoef[i]; }
    if (t < 80) sWu[t] = Wu[t];
    if (t < 16) sbu[t] = bu[t];
    if (t < 32) sbl[t] = bl[t];
    __syncthreads();
    int el = t >> 5, f = t & 31;   // 8 edge-lanes x 32 feature-lanes
    for (int c = blockIdx.x; c < NC; c += gridDim.x){
        int lo = off_c[c], hi = off_c[c + 1];
        float acc = 0.f;
        int j = lo + el;
        for (; j + 24 < hi; j += 32){             // 4 independent row-requests in flight
            int s0 = csr_c[j], s1 = csr_c[j + 8], s2 = csr_c[j + 16], s3 = csr_c[j + 24];
            acc += (float)xu16[(size_t)s0 * 32 + f] + (float)xu16[(size_t)s1 * 32 + f]
                 + (float)xu16[(size_t)s2 * 32 + f] + (float)xu16[(size_t)s3 * 32 + f];
        }
        for (; j < hi; j += 8) acc += (float)xu16[(size_t)csr_c[j] * 32 + f];
        part[t] = acc; __syncthreads();
        float inv = 1.f / (float)imax(hi - lo, 1);
        if (el == 0 && f < 21){
            float s2 = part[f];
            #pragma unroll
            for (int k = 1; k < 8; k++) s2 += part[k * 32 + f];
            s2 *= inv;
            if (f < 16) agg[f] = s2; else aggx[f - 16] = s2;
        }
        __syncthreads();
        if (t < 16){
            float d = sbu[t];
            #pragma unroll
            for (int k = 0; k < 5; k++) d += aggx[k] * sWu[t * 5 + k];
            agg[16 + t] = d;
        }
        __syncthreads();
        if (t < 32){
            float h = sbl[t];
            for (int k = 0; k < 32; k++) h += agg[k] * sWlT[k * 32 + t] + xc[c * 32 + k] * sWrT[k * 32 + t];
            hc[t] = fmaxf(h, 0.f);
        }
        __syncthreads();
        if (t < 16){
            float a = 0.f, b = 0.f;
            for (int o = 0; o < 32; o++){ float h = hc[o]; a += h * sAT[o * 16 + t]; b += h * sBT[o * 16 + t]; }
            hc2r[c * 16 + t] = a; hcWr[c * 16 + t] = b;
        }
        __syncthreads();
    }
}

// ---------------- fused user side, MFMA version ----------------

__global__ __launch_bounds__(256) void k_user_mfma(
    const int* __restrict__ off_u, const int* __restrict__ csr_u,
    const float* __restrict__ xc, const float* __restrict__ hc2r,
    const float* __restrict__ uemb, const int* __restrict__ uidx, const float* __restrict__ ux,
    const float* __restrict__ Wu, const float* __restrict__ bu,
    const float* __restrict__ Wl, const float* __restrict__ bl, const float* __restrict__ Wr, // c1r
    const float* __restrict__ Acoef /*c2e_Wl*/, const float* __restrict__ Bcoef /*c2r_Wr*/,
    const float* __restrict__ bl2 /*c2r_bl*/,
    float* __restrict__ hu2e, float* __restrict__ ou, int NU)
{
    const int t = threadIdx.x;
    const int w = t >> 6, l = t & 63;
    const int ur = l & 15;
    const int kg = l >> 4;

    half8 b1[2][2], b2[2];
    float hbias[2];
    #pragma unroll
    for (int nt = 0; nt < 2; nt++){
        int o = nt * 16 + ur;
        const float* p = Wl + o * 32 + kg * 8;
        #pragma unroll
        for (int j = 0; j < 8; j++) b1[0][nt][j] = (_Float16)p[j];
        #pragma unroll
        for (int j = 0; j < 8; j++){
            int k = kg * 8 + j;
            float v;
            if (k < 16) v = Wr[o * 32 + k];
            else if (k < 21){
                int pc = k - 16; float s = 0.f;
                for (int m = 0; m < 16; m++) s += Wr[o * 32 + 16 + m] * Wu[m * 5 + pc];
                v = s;
            } else v = 0.f;
            b1[1][nt][j] = (_Float16)v;
        }
        float s = bl[o];
        for (int m = 0; m < 16; m++) s += Wr[o * 32 + 16 + m] * bu[m];
        hbias[nt] = s;
    }
    #pragma unroll
    for (int nt = 0; nt < 2; nt++){
        const float* W = nt ? Bcoef : Acoef;
        const float* p = W + ur * 32 + kg * 8;
        #pragma unroll
        for (int j = 0; j < 8; j++) b2[nt][j] = (_Float16)p[j];
    }
    const float bl2v = bl2[ur];

    __shared__ float lds_all[4][16 * 36 + 16 * 20];
    float* hl  = lds_all[w];
    float* b0l = lds_all[w] + 16 * 36;

    const int stride = gridDim.x * 64;
    for (int u0 = blockIdx.x * 64 + w * 16; u0 < NU; u0 += stride){
        int u = u0 + ur;
        int lo = 0, n = 0;
        if (u < NU){ lo = off_u[u]; n = off_u[u + 1] - lo; }
        float a[8] = {0,0,0,0,0,0,0,0};
        float p4[4] = {0,0,0,0};
        int j = 0;
        while (__any(j < n)){
            int d0 = (j     < n) ? csr_u[lo + j]     : -1;
            int d1 = (j + 1 < n) ? csr_u[lo + j + 1] : -1;
            if (d0 >= 0){
                const float4* xr = (const float4*)(xc + (size_t)d0 * 32 + kg * 8);
                float4 x0 = xr[0], x1 = xr[1];
                float4 h4 = *(const float4*)(hc2r + (size_t)d0 * 16 + kg * 4);
                a[0]+=x0.x; a[1]+=x0.y; a[2]+=x0.z; a[3]+=x0.w;
                a[4]+=x1.x; a[5]+=x1.y; a[6]+=x1.z; a[7]+=x1.w;
                p4[0]+=h4.x; p4[1]+=h4.y; p4[2]+=h4.z; p4[3]+=h4.w;
            }
            if (d1 >= 0){
                const float4* xr = (const float4*)(xc + (size_t)d1 * 32 + kg * 8);
                float4 x0 = xr[0], x1 = xr[1];
                float4 h4 = *(const float4*)(hc2r + (size_t)d1 * 16 + kg * 4);
                a[0]+=x0.x; a[1]+=x0.y; a[2]+=x0.z; a[3]+=x0.w;
                a[4]+=x1.x; a[5]+=x1.y; a[6]+=x1.z; a[7]+=x1.w;
                p4[0]+=h4.x; p4[1]+=h4.y; p4[2]+=h4.z; p4[3]+=h4.w;
            }
            j += 2;
        }
        float inv = 1.f / (float)imax(n, 1);
        half8 a1, a2;
        #pragma unroll
        for (int q = 0; q < 8; q++) a1[q] = (_Float16)(a[q] * inv);
        #pragma unroll
        for (int q = 0; q < 8; q++) a2[q] = (_Float16)0.f;
        if (u < NU){
            if (kg < 2){
                const float4* er = (const float4*)(uemb + (size_t)uidx[u] * 16 + kg * 8);
                float4 e0 = er[0], e1 = er[1];
                a2[0]=(_Float16)e0.x; a2[1]=(_Float16)e0.y; a2[2]=(_Float16)e0.z; a2[3]=(_Float16)e0.w;
                a2[4]=(_Float16)e1.x; a2[5]=(_Float16)e1.y; a2[6]=(_Float16)e1.z; a2[7]=(_Float16)e1.w;
            } else if (kg == 2){
                #pragma unroll
                for (int q = 0; q < 5; q++) a2[q] = (_Float16)ux[(size_t)u * 5 + q];
            }
        }
        floatx4 c1[2];
        #pragma unroll
        for (int nt = 0; nt < 2; nt++){
            floatx4 c = {hbias[nt], hbias[nt], hbias[nt], hbias[nt]};
            c = __builtin_amdgcn_mfma_f32_16x16x32_f16(a1, b1[0][nt], c, 0, 0, 0);
            c = __builtin_amdgcn_mfma_f32_16x16x32_f16(a2, b1[1][nt], c, 0, 0, 0);
            c1[nt] = c;
        }
        asm volatile("s_waitcnt lgkmcnt(0)" ::: "memory");
        #pragma unroll
        for (int nt = 0; nt < 2; nt++)
            #pragma unroll
            for (int r = 0; r < 4; r++)
                hl[(kg * 4 + r) * 36 + nt * 16 + ur] = fmaxf(c1[nt][r], 0.f);
        #pragma unroll
        for (int q = 0; q < 4; q++) b0l[ur * 20 + kg * 4 + q] = p4[q] * inv;
        asm volatile("s_waitcnt lgkmcnt(0)" ::: "memory");
        half8 ah;
        {
            const float* hp = hl + ur * 36 + kg * 8;
            #pragma unroll
            for (int q = 0; q < 8; q++) ah[q] = (_Float16)hp[q];
        }
        floatx4 c20 = {0.f, 0.f, 0.f, 0.f};
        c20 = __builtin_amdgcn_mfma_f32_16x16x32_f16(ah, b2[0], c20, 0, 0, 0);
        floatx4 c21 = {bl2v, bl2v, bl2v, bl2v};
        c21 = __builtin_amdgcn_mfma_f32_16x16x32_f16(ah, b2[1], c21, 0, 0, 0);
        #pragma unroll
        for (int r = 0; r < 4; r++){
            int urow = kg * 4 + r;
            int ug = u0 + urow;
            if (ug < NU){
                hu2e[(size_t)ug * 16 + ur] = c20[r];
                ou[(size_t)ug * 16 + ur]   = c21[r] + b0l[urow * 20 + ur];
            }
        }
    }
}

// ---------------- layer 2 course side ----------------

__global__ __launch_bounds__(256) void k_course_l2(
    const int* __restrict__ off_c, const int* __restrict__ csr_c,
    const float* __restrict__ hu2e, const float* __restrict__ bl2,
    const float* __restrict__ hcWr, float* __restrict__ oc, int NC)
{
    __shared__ float part[256];
    int t = threadIdx.x; int el = t >> 4, f = t & 15;
    for (int c = blockIdx.x; c < NC; c += gridDim.x){
        int lo = off_c[c], hi = off_c[c + 1];
        float acc = 0.f;
        int j = lo + el;
        for (; j + 48 < hi; j += 64){
            acc += hu2e[csr_c[j] * 16 + f] + hu2e[csr_c[j + 16] * 16 + f]
                 + hu2e[csr_c[j + 32] * 16 + f] + hu2e[csr_c[j + 48] * 16 + f];
        }
        for (; j < hi; j += 16) acc += hu2e[csr_c[j] * 16 + f];
        part[t] = acc; __syncthreads();
        if (el == 0){
            float s = part[f];
            #pragma unroll
            for (int k = 1; k < 16; k++) s += part[k * 16 + f];
            oc[c * 16 + f] = s / (float)imax(hi - lo, 1) + bl2[f] + hcWr[c * 16 + f];
        }
        __syncthreads();
    }
}

// ---------------- decode ----------------

__global__ void k_decode(const int* __restrict__ ls, const int* __restrict__ ld,
                         const float* __restrict__ ou, const float* __restrict__ oc,
                         float* __restrict__ out, int L){
    int gt = blockIdx.x * blockDim.x + threadIdx.x;
    int l = gt >> 2, q = gt & 3;
    if (l >= L) return;
    int a = ls[l], b = ld[l];
    float4 va = ((const float4*)(ou + (size_t)a * 16))[q];
    float4 vb = ((const float4*)(oc + (size_t)b * 16))[q];
    float s = va.x * vb.x + va.y * vb.y + va.z * vb.z + va.w * vb.w;
    s += __shfl_xor(s, 1);
    s += __shfl_xor(s, 2);
    if (q == 0) out[l] = s;
}

// ---------------- launcher ----------------

extern "C" void kernel_launch(void* const* d_in, const int* in_sizes, int n_in,
                              void* d_out, int out_size, void* d_ws, size_t ws_size,
                              hipStream_t stream)
{
    const float* user_x       = (const float*)d_in[0];
    const float* course_x     = (const float*)d_in[1];
    const float* user_embed   = (const float*)d_in[2];
    const float* course_embed = (const float*)d_in[3];
    const float* Wu = (const float*)d_in[4];
    const float* bu = (const float*)d_in[5];
    const float* Wc = (const float*)d_in[6];
    const float* bc = (const float*)d_in[7];
    const float* c1e_Wl = (const float*)d_in[8];
    const float* c1e_bl = (const float*)d_in[9];
    const float* c1e_Wr = (const float*)d_in[10];
    const float* c1r_Wl = (const float*)d_in[11];
    const float* c1r_bl = (const float*)d_in[12];
    const float* c1r_Wr = (const float*)d_in[13];
    const float* c2e_Wl = (const float*)d_in[14];
    const float* c2e_bl = (const float*)d_in[15];
    const float* c2e_Wr = (const float*)d_in[16];
    const float* c2r_Wl = (const float*)d_in[17];
    const float* c2r_bl = (const float*)d_in[18];
    const float* c2r_Wr = (const float*)d_in[19];
    const int* uidx      = (const int*)d_in[20];
    const int* cidx      = (const int*)d_in[21];
    const int* edge_src  = (const int*)d_in[22];
    const int* edge_dst  = (const int*)d_in[23];
    const int* label_src = (const int*)d_in[24];
    const int* label_dst = (const int*)d_in[25];
    const int NU = in_sizes[20], NC = in_sizes[21], E = in_sizes[22], L = in_sizes[24];
    const int NBC = (NC + (1 << CSH) - 1) >> CSH;
    const int NBU = (NU + (1 << USH) - 1) >> USH;

    char* ws = (char*)d_ws;
    size_t woff = 0;
    auto alloc = [&](size_t bytes) -> char* {
        char* p = ws + woff;
        woff = (woff + bytes + 255) & ~(size_t)255;
        return p;
    };
    int*   off_u = (int*)  alloc((size_t)(NU + 1) * 4);
    int*   off_c = (int*)  alloc((size_t)(NC + 1) * 4);
    int*   csr_c = (int*)  alloc((size_t)E * 4);
    int*   csr_u = (int*)  alloc((size_t)E * 4);
    float* xc    = (float*)alloc((size_t)NC * 32 * 4);
    float* hc2r  = (float*)alloc((size_t)NC * 16 * 4);
    float* hcWr  = (float*)alloc((size_t)NC * 16 * 4);
    float* hu2e  = (float*)alloc((size_t)NU * 16 * 4);   // binned_c aliases
    float* ou    = (float*)alloc((size_t)NU * 16 * 4);   // binned_u aliases
    float* occ   = (float*)alloc((size_t)NC * 16 * 4);
    _Float16* xu16 = (_Float16*)alloc((size_t)NU * 32 * 2);
    int*   cnt_c  = (int*) alloc(MAXBIN * 4);
    int*   cnt_u  = (int*) alloc(MAXBIN * 4);
    int*   base_c = (int*) alloc(MAXBIN * 4);
    int*   base_u = (int*) alloc(MAXBIN * 4);
    int*   cur_c  = (int*) alloc(MAXBIN * 4);
    int*   cur_u  = (int*) alloc(MAXBIN * 4);
    uint2* binned_c = (uint2*)hu2e;
    uint2* binned_u = (uint2*)ou;
    (void)ws_size; (void)n_in; (void)out_size;

    int chunks = (E + 2047) / 2048;

    hipMemsetAsync(cnt_c, 0, MAXBIN * 4, stream);
    hipMemsetAsync(cnt_u, 0, MAXBIN * 4, stream);
    k_phase0<<<chunks, 256, 0, stream>>>(edge_src, edge_dst, cnt_c, cnt_u, E, NBC, NBU);
    k_xu16<<<(NU + 255) / 256, 256, 0, stream>>>(user_embed, uidx, user_x, xu16, NU);
    k_sbase<<<1, 64, 0, stream>>>(cnt_c, cnt_u, base_c, cur_c, base_u, cur_u, off_c, off_u, NC, NU, NBC, NBU, E);
    k_phase1<<<chunks, 256, 0, stream>>>(edge_src, edge_dst, cur_c, cur_u, binned_c, binned_u, E, NBC, NBU);
    k_xc<<<(NC * 32 + 255) / 256, 256, 0, stream>>>(course_x, course_embed, cidx, Wc, bc, xc, NC);
    k_p2<<<NBC + NBU, 1024, 0, stream>>>(binned_c, binned_u, cnt_c, base_c, cnt_u, base_u,
                                         off_c, csr_c, off_u, csr_u, NC, NU, NBC);
    k_course_l1<<<2048, 256, 0, stream>>>(off_c, csr_c, xu16, Wu, bu,
                                          c1e_Wl, c1e_bl, c1e_Wr, c2r_Wl, c2e_Wr, xc, hc2r, hcWr, NC);
    k_user_mfma<<<1024, 256, 0, stream>>>(off_u, csr_u, xc, hc2r, user_embed, uidx, user_x,
                                          Wu, bu, c1r_Wl, c1r_bl, c1r_Wr,
                                          c2e_Wl, c2r_Wr, c2r_bl, hu2e, ou, NU);
    k_course_l2<<<1024, 256, 0, stream>>>(off_c, csr_c, hu2e, c2e_bl, hcWr, occ, NC);
    k_decode<<<(unsigned)(((size_t)L * 4 + 255) / 256), 256, 0, stream>>>(label_src, label_dst, ou, occ, (float*)d_out, L);
}